// Round 1
// baseline (413.721 us; speedup 1.0000x reference)
//
#include <hip/hip_runtime.h>
#include <hip/hip_fp16.h>
#include <cstdint>
#include <cstddef>

#define NEG 0.2f
#define TILE 4096   // edges per partition tile

// ---------------- CSR build: hist + scan ----------------

__global__ __launch_bounds__(256) void hist_k(const int* __restrict__ ei, int* __restrict__ cnt, int E) {
    int i = blockIdx.x * 256 + threadIdx.x;
    if (i < E) atomicAdd(&cnt[__builtin_nontemporal_load(ei + E + i)], 1);
}

__global__ __launch_bounds__(256) void scan1_k(const int* __restrict__ cnt, int* __restrict__ rp,
                                               int* __restrict__ bs, int N) {
    __shared__ int sm[256];
    int t = threadIdx.x, i = blockIdx.x * 256 + t;
    int v = (i < N) ? cnt[i] : 0;
    sm[t] = v; __syncthreads();
    for (int off = 1; off < 256; off <<= 1) {
        int u = (t >= off) ? sm[t - off] : 0;
        __syncthreads();
        sm[t] += u;
        __syncthreads();
    }
    if (i < N) rp[i] = sm[t] - v;          // exclusive within block
    if (t == 255) bs[blockIdx.x] = sm[255];
}

__global__ __launch_bounds__(1024) void scan2_k(int* __restrict__ bs, int nb) {
    __shared__ int sm[1024];
    int t = threadIdx.x;
    int v = (t < nb) ? bs[t] : 0;
    sm[t] = v; __syncthreads();
    for (int off = 1; off < 1024; off <<= 1) {
        int u = (t >= off) ? sm[t - off] : 0;
        __syncthreads();
        sm[t] += u;
        __syncthreads();
    }
    if (t < nb) bs[t] = sm[t] - v;         // exclusive block offsets
}

__global__ __launch_bounds__(256) void scan3_k(int* __restrict__ rp, const int* __restrict__ bs, int N) {
    int i = blockIdx.x * 256 + threadIdx.x;
    if (i < N) rp[i] += bs[blockIdx.x];
}

__global__ __launch_bounds__(256) void initA_k(const int* __restrict__ rp, int* __restrict__ curA, int nbk) {
    int b = threadIdx.x;
    if (b < nbk) curA[b] = rp[b << 9];
}

// ---------------- Phase A: LDS-staged partition of edges into 512-node buckets ----------------

__global__ __launch_bounds__(256) void partA_k(const int* __restrict__ ei, int* __restrict__ curA,
                                               uint2* __restrict__ pairs, int E, int nbk) {
    __shared__ int scnt[256];
    __shared__ int sc[256];
    __shared__ int sbase[256];
    __shared__ int gbase[256];
    __shared__ int cur2[256];
    __shared__ int ssrc[TILE];
    __shared__ int sdst[TILE];
    int t = threadIdx.x;
    int ntiles = (E + TILE - 1) / TILE;
    for (int tile = blockIdx.x; tile < ntiles; tile += gridDim.x) {
        int base = tile * TILE;
        int cntE = min(TILE, E - base);
        scnt[t] = 0;
        __syncthreads();
        int mys[16], myd[16];
        #pragma unroll
        for (int j = 0; j < 16; j++) {
            int i = base + t + 256 * j;
            int s = 0, d = -1;
            if (i < E) {
                s = __builtin_nontemporal_load(ei + i);
                d = __builtin_nontemporal_load(ei + E + i);
            }
            mys[j] = s; myd[j] = d;
            if (d >= 0) atomicAdd(&scnt[d >> 9], 1);
        }
        __syncthreads();
        sc[t] = scnt[t];
        __syncthreads();
        for (int off = 1; off < 256; off <<= 1) {
            int u = (t >= off) ? sc[t - off] : 0;
            __syncthreads();
            sc[t] += u;
            __syncthreads();
        }
        int myb = sc[t] - scnt[t];
        sbase[t] = myb;
        cur2[t] = myb;
        if (t < nbk && scnt[t] > 0) gbase[t] = atomicAdd(&curA[t], scnt[t]);
        __syncthreads();
        #pragma unroll
        for (int j = 0; j < 16; j++) {
            int d = myd[j];
            if (d >= 0) {
                int b = d >> 9;
                int pos = atomicAdd(&cur2[b], 1);
                ssrc[pos] = mys[j];
                sdst[pos] = d;
            }
        }
        __syncthreads();
        for (int i = t; i < cntE; i += 256) {
            int d = sdst[i];
            int b = d >> 9;
            int addr = gbase[b] + (i - sbase[b]);
            pairs[addr] = make_uint2((unsigned)ssrc[i], (unsigned)d);
        }
        __syncthreads();
    }
}

// ---------------- Phase B: per-bucket scatter to per-node CSR positions ----------------

__global__ __launch_bounds__(256) void partB_pairs_k(const uint2* __restrict__ pin, const int* __restrict__ rp,
                                                     int* __restrict__ srcout, int E, int N) {
    __shared__ int cur[512];
    int b = blockIdx.x;
    int t = threadIdx.x;
    int d0 = b << 9;
    cur[t] = 0; cur[t + 256] = 0;
    __syncthreads();
    int hi = d0 + 512;
    int ebase = rp[d0];
    int eend = (hi >= N) ? E : rp[hi];
    for (int j = ebase + t; j < eend; j += 256) {
        uint2 p = pin[j];
        int d = (int)p.y;
        int pos = rp[d] + atomicAdd(&cur[d - d0], 1);
        srcout[pos] = (int)p.x;
    }
}

// ---------------- Layer 1 GEMM: h1 = x @ W1 (fp16 out), register-tiled ----------------

__global__ __launch_bounds__(256) void gemm1_k(const float* __restrict__ x, const float* __restrict__ W,
                                               const float* __restrict__ a_src, const float* __restrict__ a_dst,
                                               __half* __restrict__ h, float* __restrict__ alsrc,
                                               float* __restrict__ aldst, int N) {
    __shared__ float Bs[128 * 64];
    __shared__ float xs[64][68];
    int t = threadIdx.x;
    for (int i = t; i < 128 * 64 / 4; i += 256)
        ((float4*)Bs)[i] = ((const float4*)W)[i];
    int ct = t & 15, rt = t >> 4;
    int head = ct >> 2, cq = ct & 3;
    float asv[4], adv[4];
    #pragma unroll
    for (int j = 0; j < 4; j++) {
        asv[j] = a_src[head * 16 + 4 * cq + j];
        adv[j] = a_dst[head * 16 + 4 * cq + j];
    }
    int ntiles = (N + 63) >> 6;
    for (int tile = blockIdx.x; tile < ntiles; tile += gridDim.x) {
        int r0 = tile << 6;
        float acc[4][4];
        #pragma unroll
        for (int i = 0; i < 4; i++)
            #pragma unroll
            for (int j = 0; j < 4; j++) acc[i][j] = 0.f;
        for (int kc = 0; kc < 128; kc += 64) {
            __syncthreads();
            int srow = t >> 4, sf4 = t & 15;
            #pragma unroll
            for (int p = 0; p < 4; p++) {
                int r = r0 + srow + 16 * p;
                float4 v = make_float4(0.f, 0.f, 0.f, 0.f);
                if (r < N) v = *(const float4*)(x + (size_t)r * 128 + kc + 4 * sf4);
                *(float4*)&xs[srow + 16 * p][4 * sf4] = v;
            }
            __syncthreads();
            #pragma unroll 4
            for (int k = 0; k < 64; k++) {
                float4 bv = *(float4*)&Bs[(kc + k) * 64 + 4 * ct];
                #pragma unroll
                for (int i = 0; i < 4; i++) {
                    float xv = xs[4 * rt + i][k];
                    acc[i][0] = fmaf(xv, bv.x, acc[i][0]);
                    acc[i][1] = fmaf(xv, bv.y, acc[i][1]);
                    acc[i][2] = fmaf(xv, bv.z, acc[i][2]);
                    acc[i][3] = fmaf(xv, bv.w, acc[i][3]);
                }
            }
        }
        #pragma unroll
        for (int i = 0; i < 4; i++) {
            int r = r0 + 4 * rt + i;
            float ps = 0.f, pd = 0.f;
            #pragma unroll
            for (int j = 0; j < 4; j++) {
                ps = fmaf(acc[i][j], asv[j], ps);
                pd = fmaf(acc[i][j], adv[j], pd);
            }
            ps += __shfl_xor(ps, 1); ps += __shfl_xor(ps, 2);
            pd += __shfl_xor(pd, 1); pd += __shfl_xor(pd, 2);
            if (r < N) {
                __half2 h0 = __floats2half2_rn(acc[i][0], acc[i][1]);
                __half2 h1 = __floats2half2_rn(acc[i][2], acc[i][3]);
                *(__half2*)(h + (size_t)r * 64 + 4 * ct) = h0;
                *(__half2*)(h + (size_t)r * 64 + 4 * ct + 2) = h1;
                if (cq == 0) { alsrc[r * 4 + head] = ps; aldst[r * 4 + head] = pd; }
            }
        }
    }
}

// ---------------- Layer 1 node aggregation: quarter-wave per node, 4-deep edge pipeline ----------------

__global__ __launch_bounds__(256) void node1_k(const __half* __restrict__ h, const int* __restrict__ srccol,
                                               const float* __restrict__ alsrc, const float* __restrict__ aldst,
                                               const int* __restrict__ rp, const int* __restrict__ cnt,
                                               const float* __restrict__ bias, __half* __restrict__ out, int N) {
    int t = threadIdx.x;
    int d = (blockIdx.x * 256 + t) >> 4;
    if (d >= N) return;
    int c = t & 15;
    int hc = c >> 2;
    const __half2* hb = (const __half2*)h;
    unsigned co = 2u * c;
    float ad = aldst[d * 4 + hc];
    float e = alsrc[d * 4 + hc] + ad;
    float w = __expf(e > 0.f ? e : NEG * e);
    float den = w;
    __half2 wp = __float2half2_rn(w);
    uint2 u = *(const uint2*)(hb + ((unsigned)d << 5) + co);
    __half2 acc0 = __hmul2(wp, *(__half2*)&u.x);
    __half2 acc1 = __hmul2(wp, *(__half2*)&u.y);
    int start = rp[d], deg = cnt[d];
    int i = 0;
    for (; i + 3 < deg; i += 4) {
        int s0 = srccol[start + i];
        int s1 = srccol[start + i + 1];
        int s2 = srccol[start + i + 2];
        int s3 = srccol[start + i + 3];
        uint2 u0 = *(const uint2*)(hb + ((unsigned)s0 << 5) + co);
        uint2 u1 = *(const uint2*)(hb + ((unsigned)s1 << 5) + co);
        uint2 u2 = *(const uint2*)(hb + ((unsigned)s2 << 5) + co);
        uint2 u3 = *(const uint2*)(hb + ((unsigned)s3 << 5) + co);
        float e0 = alsrc[s0 * 4 + hc] + ad;
        float e1 = alsrc[s1 * 4 + hc] + ad;
        float e2 = alsrc[s2 * 4 + hc] + ad;
        float e3 = alsrc[s3 * 4 + hc] + ad;
        float w0 = __expf(e0 > 0.f ? e0 : NEG * e0);
        float w1 = __expf(e1 > 0.f ? e1 : NEG * e1);
        float w2 = __expf(e2 > 0.f ? e2 : NEG * e2);
        float w3 = __expf(e3 > 0.f ? e3 : NEG * e3);
        den += (w0 + w1) + (w2 + w3);
        __half2 p0 = __float2half2_rn(w0), p1 = __float2half2_rn(w1);
        __half2 p2 = __float2half2_rn(w2), p3 = __float2half2_rn(w3);
        acc0 = __hfma2(p0, *(__half2*)&u0.x, acc0);
        acc1 = __hfma2(p0, *(__half2*)&u0.y, acc1);
        acc0 = __hfma2(p1, *(__half2*)&u1.x, acc0);
        acc1 = __hfma2(p1, *(__half2*)&u1.y, acc1);
        acc0 = __hfma2(p2, *(__half2*)&u2.x, acc0);
        acc1 = __hfma2(p2, *(__half2*)&u2.y, acc1);
        acc0 = __hfma2(p3, *(__half2*)&u3.x, acc0);
        acc1 = __hfma2(p3, *(__half2*)&u3.y, acc1);
    }
    for (; i < deg; i++) {
        int s = srccol[start + i];
        uint2 us = *(const uint2*)(hb + ((unsigned)s << 5) + co);
        float es = alsrc[s * 4 + hc] + ad;
        float ws = __expf(es > 0.f ? es : NEG * es);
        den += ws;
        __half2 wps = __float2half2_rn(ws);
        acc0 = __hfma2(wps, *(__half2*)&us.x, acc0);
        acc1 = __hfma2(wps, *(__half2*)&us.y, acc1);
    }
    float inv = 1.f / den;
    float2 f0 = __half22float2(acc0), f1 = __half22float2(acc1);
    float4 b = *(const float4*)(bias + 4 * c);
    __half2 o0 = __floats2half2_rn(f0.x * inv + b.x, f0.y * inv + b.y);
    __half2 o1 = __floats2half2_rn(f1.x * inv + b.z, f1.y * inv + b.w);
    uint2 o; o.x = *(unsigned*)&o0; o.y = *(unsigned*)&o1;
    *(uint2*)(out + (size_t)d * 64 + 4 * c) = o;
}

// ---------------- Folded attention-logit weights: w_as[k][h] = sum_c W2[k, h*32+c]*a_src2[h,c] ----------------

__global__ __launch_bounds__(256) void prew_k(const float* __restrict__ W2, const float* __restrict__ as2,
                                              const float* __restrict__ ad2, float* __restrict__ was,
                                              float* __restrict__ wad) {
    int t = threadIdx.x;          // t = k*4 + h, k in [0,64), h in [0,4)
    int k = t >> 2, hh = t & 3;
    const float* wrow = W2 + k * 128 + hh * 32;
    const float* av = as2 + hh * 32;
    const float* dv = ad2 + hh * 32;
    float s = 0.f, ds = 0.f;
    #pragma unroll 8
    for (int c = 0; c < 32; c++) {
        float w = wrow[c];
        s = fmaf(w, av[c], s);
        ds = fmaf(w, dv[c], ds);
    }
    was[t] = s;
    wad[t] = ds;
}

// ---------------- alv2: alsrc2[d,h] = h1o[d,:] . w_as[:,h] (quarter-wave per node) ----------------

__global__ __launch_bounds__(256) void alv2_k(const __half* __restrict__ h1o, const float* __restrict__ was,
                                              const float* __restrict__ wad, float* __restrict__ alsrc,
                                              float* __restrict__ aldst, int N) {
    int t = threadIdx.x;
    int d = (blockIdx.x * 256 + t) >> 4;
    if (d >= N) return;
    int c = t & 15;                       // lane owns dims 4c..4c+3
    uint2 u = *(const uint2*)(h1o + (size_t)d * 64 + 4 * c);
    float2 f0 = __half22float2(*(__half2*)&u.x);
    float2 f1 = __half22float2(*(__half2*)&u.y);
    float v0 = f0.x, v1 = f0.y, v2 = f1.x, v3 = f1.y;
    const float4* was4 = (const float4*)was;
    const float4* wad4 = (const float4*)wad;
    float4 wa0 = was4[4 * c + 0], wa1 = was4[4 * c + 1], wa2 = was4[4 * c + 2], wa3 = was4[4 * c + 3];
    float4 wd0 = wad4[4 * c + 0], wd1 = wad4[4 * c + 1], wd2 = wad4[4 * c + 2], wd3 = wad4[4 * c + 3];
    float4 ps, pd;
    ps.x = fmaf(v0, wa0.x, fmaf(v1, wa1.x, fmaf(v2, wa2.x, v3 * wa3.x)));
    ps.y = fmaf(v0, wa0.y, fmaf(v1, wa1.y, fmaf(v2, wa2.y, v3 * wa3.y)));
    ps.z = fmaf(v0, wa0.z, fmaf(v1, wa1.z, fmaf(v2, wa2.z, v3 * wa3.z)));
    ps.w = fmaf(v0, wa0.w, fmaf(v1, wa1.w, fmaf(v2, wa2.w, v3 * wa3.w)));
    pd.x = fmaf(v0, wd0.x, fmaf(v1, wd1.x, fmaf(v2, wd2.x, v3 * wd3.x)));
    pd.y = fmaf(v0, wd0.y, fmaf(v1, wd1.y, fmaf(v2, wd2.y, v3 * wd3.y)));
    pd.z = fmaf(v0, wd0.z, fmaf(v1, wd1.z, fmaf(v2, wd2.z, v3 * wd3.z)));
    pd.w = fmaf(v0, wd0.w, fmaf(v1, wd1.w, fmaf(v2, wd2.w, v3 * wd3.w)));
    #pragma unroll
    for (int off = 1; off <= 8; off <<= 1) {
        ps.x += __shfl_xor(ps.x, off); ps.y += __shfl_xor(ps.y, off);
        ps.z += __shfl_xor(ps.z, off); ps.w += __shfl_xor(ps.w, off);
        pd.x += __shfl_xor(pd.x, off); pd.y += __shfl_xor(pd.y, off);
        pd.z += __shfl_xor(pd.z, off); pd.w += __shfl_xor(pd.w, off);
    }
    if (c == 0) {
        *(float4*)(alsrc + (size_t)d * 4) = ps;
        *(float4*)(aldst + (size_t)d * 4) = pd;
    }
}

// ---------------- Layer 2 node aggregation over h1o (pre-W2): one head per lane-quad ----------------
// z_h[d,:] = sum_s w_sh * h1o[s,:];  y[d, h*64+k] = z_h[d,k] * 0.25/den_h

#define ACC8(P, A, B) { const __half2* qa = (const __half2*)&(A); const __half2* qb = (const __half2*)&(B); \
    acc0 = __hfma2(P, qa[0], acc0); acc1 = __hfma2(P, qa[1], acc1); \
    acc2 = __hfma2(P, qa[2], acc2); acc3 = __hfma2(P, qa[3], acc3); \
    acc4 = __hfma2(P, qb[0], acc4); acc5 = __hfma2(P, qb[1], acc5); \
    acc6 = __hfma2(P, qb[2], acc6); acc7 = __hfma2(P, qb[3], acc7); }

__global__ __launch_bounds__(256) void node2_k(const __half* __restrict__ h1o, const int* __restrict__ srccol,
                                               const float* __restrict__ alsrc, const float* __restrict__ aldst,
                                               const int* __restrict__ rp, const int* __restrict__ cnt,
                                               __half* __restrict__ y, int N) {
    int t = threadIdx.x;
    int d = (blockIdx.x * 256 + t) >> 4;
    if (d >= N) return;
    int c = t & 15;
    int h = c >> 2;                           // head
    unsigned co = 2u * (unsigned)(c & 3);     // uint4 offset in 8-uint4 row (16-half slice)
    const uint4* hb = (const uint4*)h1o;
    float ad = aldst[d * 4 + h];
    float e = alsrc[d * 4 + h] + ad;
    float w = __expf(e > 0.f ? e : NEG * e);
    float den = w;
    __half2 wp = __float2half2_rn(w);
    uint4 ua = hb[((unsigned)d << 3) + co];
    uint4 ub = hb[((unsigned)d << 3) + co + 1];
    const __half2* pa = (const __half2*)&ua;
    const __half2* pb = (const __half2*)&ub;
    __half2 acc0 = __hmul2(wp, pa[0]), acc1 = __hmul2(wp, pa[1]);
    __half2 acc2 = __hmul2(wp, pa[2]), acc3 = __hmul2(wp, pa[3]);
    __half2 acc4 = __hmul2(wp, pb[0]), acc5 = __hmul2(wp, pb[1]);
    __half2 acc6 = __hmul2(wp, pb[2]), acc7 = __hmul2(wp, pb[3]);
    int start = rp[d], deg = cnt[d];
    int i = 0;
    for (; i + 3 < deg; i += 4) {
        int s0 = srccol[start + i];
        int s1 = srccol[start + i + 1];
        int s2 = srccol[start + i + 2];
        int s3 = srccol[start + i + 3];
        uint4 a0 = hb[((unsigned)s0 << 3) + co], b0 = hb[((unsigned)s0 << 3) + co + 1];
        uint4 a1 = hb[((unsigned)s1 << 3) + co], b1 = hb[((unsigned)s1 << 3) + co + 1];
        uint4 a2 = hb[((unsigned)s2 << 3) + co], b2 = hb[((unsigned)s2 << 3) + co + 1];
        uint4 a3 = hb[((unsigned)s3 << 3) + co], b3 = hb[((unsigned)s3 << 3) + co + 1];
        float e0 = alsrc[s0 * 4 + h] + ad;
        float e1 = alsrc[s1 * 4 + h] + ad;
        float e2 = alsrc[s2 * 4 + h] + ad;
        float e3 = alsrc[s3 * 4 + h] + ad;
        float w0 = __expf(e0 > 0.f ? e0 : NEG * e0);
        float w1 = __expf(e1 > 0.f ? e1 : NEG * e1);
        float w2 = __expf(e2 > 0.f ? e2 : NEG * e2);
        float w3 = __expf(e3 > 0.f ? e3 : NEG * e3);
        den += (w0 + w1) + (w2 + w3);
        __half2 p0 = __float2half2_rn(w0), p1 = __float2half2_rn(w1);
        __half2 p2 = __float2half2_rn(w2), p3 = __float2half2_rn(w3);
        ACC8(p0, a0, b0)
        ACC8(p1, a1, b1)
        ACC8(p2, a2, b2)
        ACC8(p3, a3, b3)
    }
    for (; i < deg; i++) {
        int s = srccol[start + i];
        uint4 as = hb[((unsigned)s << 3) + co], bs = hb[((unsigned)s << 3) + co + 1];
        float es = alsrc[s * 4 + h] + ad;
        float ws = __expf(es > 0.f ? es : NEG * es);
        den += ws;
        __half2 pws = __float2half2_rn(ws);
        ACC8(pws, as, bs)
    }
    float inv = 0.25f / den;
    __half2 ip = __float2half2_rn(inv);
    uint4 oA, oB;
    __half2* oa = (__half2*)&oA; __half2* ob = (__half2*)&oB;
    oa[0] = __hmul2(ip, acc0); oa[1] = __hmul2(ip, acc1);
    oa[2] = __hmul2(ip, acc2); oa[3] = __hmul2(ip, acc3);
    ob[0] = __hmul2(ip, acc4); ob[1] = __hmul2(ip, acc5);
    ob[2] = __hmul2(ip, acc6); ob[3] = __hmul2(ip, acc7);
    __half* yp = y + (size_t)d * 256 + 16u * (unsigned)c;
    *(uint4*)yp = oA;
    *(uint4*)(yp + 8) = oB;
}

// ---------------- Final: out = logsoftmax(elu(y @ W2s + b2)) ; W2s[h*64+k][c] = W2[k][h*32+c] ----------------

__global__ __launch_bounds__(256) void gemm3_k(const __half* __restrict__ y, const float* __restrict__ W2,
                                               const float* __restrict__ bias, float* __restrict__ out, int N) {
    __shared__ __half2 ws[256 * 16];      // [k'][c2]: cols 2c2,2c2+1
    __shared__ __half2 ys[64 * 134];      // [row][k2], pad 134 (bank-spread, 8B aligned)
    int t = threadIdx.x;
    for (int i = t; i < 4096; i += 256) {
        int kp = i >> 4, c2 = i & 15;
        int hh = kp >> 6, kk = kp & 63;
        const float* wp = W2 + kk * 128 + hh * 32 + 2 * c2;
        ws[i] = __floats2half2_rn(wp[0], wp[1]);
    }
    int ct = t & 7, rt = t >> 3;          // cols 4ct..4ct+3; rows 2rt,2rt+1
    float4 b4 = *(const float4*)(bias + 4 * ct);
    int ntiles = (N + 63) >> 6;
    for (int tile = blockIdx.x; tile < ntiles; tile += gridDim.x) {
        int r0 = tile << 6;
        __syncthreads();
        for (int i = t; i < 64 * 64; i += 256) {
            int row = i >> 6, k4 = i & 63;
            uint2 v = make_uint2(0u, 0u);
            int r = r0 + row;
            if (r < N) v = *(const uint2*)(y + (size_t)r * 256 + 4 * k4);
            *(uint2*)&ys[row * 134 + 2 * k4] = v;
        }
        __syncthreads();
        float acc[2][4];
        #pragma unroll
        for (int r = 0; r < 2; r++)
            #pragma unroll
            for (int j = 0; j < 4; j++) acc[r][j] = 0.f;
        const __half2* yr0 = ys + (2 * rt) * 134;
        const __half2* yr1 = ys + (2 * rt + 1) * 134;
        #pragma unroll 4
        for (int k2 = 0; k2 < 128; k2++) {
            const __half2* wk0 = ws + (2 * k2) * 16;
            const __half2* wk1 = wk0 + 16;
            float2 wA0 = __half22float2(wk0[2 * ct]);
            float2 wA1 = __half22float2(wk0[2 * ct + 1]);
            float2 wB0 = __half22float2(wk1[2 * ct]);
            float2 wB1 = __half22float2(wk1[2 * ct + 1]);
            float2 xa = __half22float2(yr0[k2]);
            float2 xb = __half22float2(yr1[k2]);
            acc[0][0] = fmaf(xa.x, wA0.x, acc[0][0]); acc[0][1] = fmaf(xa.x, wA0.y, acc[0][1]);
            acc[0][2] = fmaf(xa.x, wA1.x, acc[0][2]); acc[0][3] = fmaf(xa.x, wA1.y, acc[0][3]);
            acc[0][0] = fmaf(xa.y, wB0.x, acc[0][0]); acc[0][1] = fmaf(xa.y, wB0.y, acc[0][1]);
            acc[0][2] = fmaf(xa.y, wB1.x, acc[0][2]); acc[0][3] = fmaf(xa.y, wB1.y, acc[0][3]);
            acc[1][0] = fmaf(xb.x, wA0.x, acc[1][0]); acc[1][1] = fmaf(xb.x, wA0.y, acc[1][1]);
            acc[1][2] = fmaf(xb.x, wA1.x, acc[1][2]); acc[1][3] = fmaf(xb.x, wA1.y, acc[1][3]);
            acc[1][0] = fmaf(xb.y, wB0.x, acc[1][0]); acc[1][1] = fmaf(xb.y, wB0.y, acc[1][1]);
            acc[1][2] = fmaf(xb.y, wB1.x, acc[1][2]); acc[1][3] = fmaf(xb.y, wB1.y, acc[1][3]);
        }
        #pragma unroll
        for (int r = 0; r < 2; r++) {
            int row = r0 + 2 * rt + r;
            float ev0 = acc[r][0] + b4.x;
            float ev1 = acc[r][1] + b4.y;
            float ev2 = acc[r][2] + b4.z;
            float ev3 = acc[r][3] + b4.w;
            ev0 = ev0 > 0.f ? ev0 : __expf(ev0) - 1.f;
            ev1 = ev1 > 0.f ? ev1 : __expf(ev1) - 1.f;
            ev2 = ev2 > 0.f ? ev2 : __expf(ev2) - 1.f;
            ev3 = ev3 > 0.f ? ev3 : __expf(ev3) - 1.f;
            float mx = fmaxf(fmaxf(ev0, ev1), fmaxf(ev2, ev3));
            #pragma unroll
            for (int off = 1; off <= 4; off <<= 1) mx = fmaxf(mx, __shfl_xor(mx, off));
            float sm = __expf(ev0 - mx) + __expf(ev1 - mx) + __expf(ev2 - mx) + __expf(ev3 - mx);
            #pragma unroll
            for (int off = 1; off <= 4; off <<= 1) sm += __shfl_xor(sm, off);
            float ls = mx + __logf(sm);
            if (row < N) {
                float4 o;
                o.x = ev0 - ls; o.y = ev1 - ls; o.z = ev2 - ls; o.w = ev3 - ls;
                *(float4*)(out + (size_t)row * 32 + 4 * ct) = o;
            }
        }
    }
}

// ---------------- launch ----------------

extern "C" void kernel_launch(void* const* d_in, const int* in_sizes, int n_in,
                              void* d_out, int out_size, void* d_ws, size_t ws_size,
                              hipStream_t stream) {
    const float* x   = (const float*)d_in[0];
    const int*   ei  = (const int*)d_in[1];
    const float* W1  = (const float*)d_in[2];
    const float* as1 = (const float*)d_in[3];
    const float* ad1 = (const float*)d_in[4];
    const float* b1  = (const float*)d_in[5];
    const float* W2  = (const float*)d_in[6];
    const float* as2 = (const float*)d_in[7];
    const float* ad2 = (const float*)d_in[8];
    const float* b2  = (const float*)d_in[9];
    float* out = (float*)d_out;
    int N = in_sizes[0] / 128;
    int E = in_sizes[1] / 2;

    char* base = (char*)d_ws;
    size_t off = 0;
    auto alloc = [&](size_t bytes) -> char* {
        char* p = base + off;
        off = (off + bytes + 255) & ~(size_t)255;
        return p;
    };
    // y [N,256] fp16 (51.2MB) overlays h1h [N,64] fp16 (dead after node1) and
    // pairs [E] uint2 (dead after partB): both are fully consumed before node2 writes y.
    __half* y     = (__half*)alloc((size_t)N * 256 * 2);
    __half* h1h   = (__half*)y;
    uint2*  pairs = (uint2*)((char*)y + (size_t)N * 64 * 2);
    __half* h1o   = (__half*)alloc((size_t)N * 64 * 2);
    float* alsrc1 = (float*)alloc((size_t)N * 4 * 4);
    float* aldst1 = (float*)alloc((size_t)N * 4 * 4);
    float* alsrc2 = (float*)alloc((size_t)N * 4 * 4);
    float* aldst2 = (float*)alloc((size_t)N * 4 * 4);
    float* was    = (float*)alloc(256 * 4);
    float* wad    = (float*)alloc(256 * 4);
    int* cnt  = (int*)alloc((size_t)N * 4);
    int* rp   = (int*)alloc((size_t)N * 4);
    int* curA = (int*)alloc(256 * 4);
    int* bs   = (int*)alloc(1024 * 4);
    int* srccol = (int*)alloc((size_t)E * 4);

    int nbk = (N + 511) >> 9;       // 512-node buckets
    int ntilesA = (E + TILE - 1) / TILE;
    int nb = (N + 255) / 256;

    prew_k<<<1, 256, 0, stream>>>(W2, as2, ad2, was, wad);
    hipMemsetAsync(cnt, 0, (size_t)N * 4, stream);
    hist_k<<<(E + 255) / 256, 256, 0, stream>>>(ei, cnt, E);
    scan1_k<<<nb, 256, 0, stream>>>(cnt, rp, bs, N);
    scan2_k<<<1, 1024, 0, stream>>>(bs, nb);
    scan3_k<<<nb, 256, 0, stream>>>(rp, bs, N);
    initA_k<<<1, 256, 0, stream>>>(rp, curA, nbk);
    partA_k<<<ntilesA, 256, 0, stream>>>(ei, curA, pairs, E, nbk);
    partB_pairs_k<<<nbk, 256, 0, stream>>>(pairs, rp, srccol, E, N);

    gemm1_k<<<768, 256, 0, stream>>>(x, W1, as1, ad1, h1h, alsrc1, aldst1, N);
    node1_k<<<(N + 15) / 16, 256, 0, stream>>>(h1h, srccol, alsrc1, aldst1, rp, cnt, b1, h1o, N);
    alv2_k<<<(N + 15) / 16, 256, 0, stream>>>(h1o, was, wad, alsrc2, aldst2, N);
    node2_k<<<(N + 15) / 16, 256, 0, stream>>>(h1o, srccol, alsrc2, aldst2, rp, cnt, y, N);
    gemm3_k<<<768, 256, 0, stream>>>(y, W2, b2, out, N);
}

// Round 2
// 351.299 us; speedup vs baseline: 1.1777x; 1.1777x over previous
//
#include <hip/hip_runtime.h>
#include <hip/hip_fp16.h>
#include <cstdint>
#include <cstddef>

#define NEG 0.2f
#define TILE 4096   // edges per partition tile
#define WEXP(e) __expf((e) > 0.f ? (e) : NEG * (e))

// ---------------- Bucket histogram (LDS-privatized): bc[b] = #edges with dst in bucket b ----------------

__global__ __launch_bounds__(256) void bhist_k(const int* __restrict__ ei, int* __restrict__ bc, int E, int nbk) {
    __shared__ int sb[256];
    int t = threadIdx.x;
    sb[t] = 0;
    __syncthreads();
    int stride = gridDim.x * 256;
    for (int i = blockIdx.x * 256 + t; i < E; i += stride) {
        int d = __builtin_nontemporal_load(ei + E + i);
        atomicAdd(&sb[d >> 9], 1);
    }
    __syncthreads();
    if (t < nbk && sb[t] > 0) atomicAdd(&bc[t], sb[t]);
}

// ---------------- Bucket scan: bb[b] = exclusive scan of bc; curA[b] = bb[b]; bb[nbk] = E ----------------

__global__ __launch_bounds__(256) void bscan_k(const int* __restrict__ bc, int* __restrict__ bb,
                                               int* __restrict__ curA, int nbk) {
    __shared__ int sm[256];
    int t = threadIdx.x;
    int v = (t < nbk) ? bc[t] : 0;
    sm[t] = v; __syncthreads();
    for (int off = 1; off < 256; off <<= 1) {
        int u = (t >= off) ? sm[t - off] : 0;
        __syncthreads();
        sm[t] += u;
        __syncthreads();
    }
    if (t < nbk) {
        int ex = sm[t] - v;
        bb[t] = ex;
        curA[t] = ex;
        if (t == nbk - 1) bb[nbk] = sm[t];
    }
}

// ---------------- Phase A: LDS-staged partition of edges into 512-node buckets ----------------

__global__ __launch_bounds__(256) void partA_k(const int* __restrict__ ei, int* __restrict__ curA,
                                               uint2* __restrict__ pairs, int E, int nbk) {
    __shared__ int scnt[256];
    __shared__ int sc[256];
    __shared__ int sbase[256];
    __shared__ int gbase[256];
    __shared__ int cur2[256];
    __shared__ int ssrc[TILE];
    __shared__ int sdst[TILE];
    int t = threadIdx.x;
    int ntiles = (E + TILE - 1) / TILE;
    for (int tile = blockIdx.x; tile < ntiles; tile += gridDim.x) {
        int base = tile * TILE;
        int cntE = min(TILE, E - base);
        scnt[t] = 0;
        __syncthreads();
        int mys[16], myd[16];
        #pragma unroll
        for (int j = 0; j < 16; j++) {
            int i = base + t + 256 * j;
            int s = 0, d = -1;
            if (i < E) {
                s = __builtin_nontemporal_load(ei + i);
                d = __builtin_nontemporal_load(ei + E + i);
            }
            mys[j] = s; myd[j] = d;
            if (d >= 0) atomicAdd(&scnt[d >> 9], 1);
        }
        __syncthreads();
        sc[t] = scnt[t];
        __syncthreads();
        for (int off = 1; off < 256; off <<= 1) {
            int u = (t >= off) ? sc[t - off] : 0;
            __syncthreads();
            sc[t] += u;
            __syncthreads();
        }
        int myb = sc[t] - scnt[t];
        sbase[t] = myb;
        cur2[t] = myb;
        if (t < nbk && scnt[t] > 0) gbase[t] = atomicAdd(&curA[t], scnt[t]);
        __syncthreads();
        #pragma unroll
        for (int j = 0; j < 16; j++) {
            int d = myd[j];
            if (d >= 0) {
                int b = d >> 9;
                int pos = atomicAdd(&cur2[b], 1);
                ssrc[pos] = mys[j];
                sdst[pos] = d;
            }
        }
        __syncthreads();
        for (int i = t; i < cntE; i += 256) {
            int d = sdst[i];
            int b = d >> 9;
            int addr = gbase[b] + (i - sbase[b]);
            pairs[addr] = make_uint2((unsigned)ssrc[i], (unsigned)d);
        }
        __syncthreads();
    }
}

// ---------------- Phase B (two-pass): per-node count + scan -> rp/cnt, then scatter ----------------

__global__ __launch_bounds__(256) void partB2_k(const uint2* __restrict__ pin, const int* __restrict__ bb,
                                                int* __restrict__ rp, int* __restrict__ cnt,
                                                int* __restrict__ srcout, int N) {
    __shared__ int cur[512];
    __shared__ int sc[512];
    int b = blockIdx.x, t = threadIdx.x;
    int d0 = b << 9;
    cur[t] = 0; cur[t + 256] = 0;
    __syncthreads();
    int ebase = bb[b], eend = bb[b + 1];
    for (int j = ebase + t; j < eend; j += 256) {
        int d = (int)pin[j].y;
        atomicAdd(&cur[d - d0], 1);
    }
    __syncthreads();
    sc[t] = cur[t]; sc[t + 256] = cur[t + 256];
    __syncthreads();
    for (int off = 1; off <= 256; off <<= 1) {
        int a0 = (t >= off) ? sc[t - off] : 0;
        int a1 = sc[t + 256 - off];
        __syncthreads();
        sc[t] += a0; sc[t + 256] += a1;
        __syncthreads();
    }
    // sc = inclusive scan; node base = ebase + sc - cur
    int base0 = ebase + sc[t] - cur[t];
    int base1 = ebase + sc[t + 256] - cur[t + 256];
    if (d0 + t < N)       { rp[d0 + t] = base0;       cnt[d0 + t] = cur[t]; }
    if (d0 + t + 256 < N) { rp[d0 + t + 256] = base1; cnt[d0 + t + 256] = cur[t + 256]; }
    cur[t] = base0; cur[t + 256] = base1;
    __syncthreads();
    for (int j = ebase + t; j < eend; j += 256) {
        uint2 p = pin[j];
        int d = (int)p.y;
        int pos = atomicAdd(&cur[d - d0], 1);
        srcout[pos] = (int)p.x;
    }
}

// ---------------- Layer 1 GEMM: h1 = x @ W1 (fp16 out), register-tiled ----------------

__global__ __launch_bounds__(256) void gemm1_k(const float* __restrict__ x, const float* __restrict__ W,
                                               const float* __restrict__ a_src, const float* __restrict__ a_dst,
                                               __half* __restrict__ h, float* __restrict__ alsrc,
                                               float* __restrict__ aldst, int N) {
    __shared__ float Bs[128 * 64];
    __shared__ float xs[64][68];
    int t = threadIdx.x;
    for (int i = t; i < 128 * 64 / 4; i += 256)
        ((float4*)Bs)[i] = ((const float4*)W)[i];
    int ct = t & 15, rt = t >> 4;
    int head = ct >> 2, cq = ct & 3;
    float asv[4], adv[4];
    #pragma unroll
    for (int j = 0; j < 4; j++) {
        asv[j] = a_src[head * 16 + 4 * cq + j];
        adv[j] = a_dst[head * 16 + 4 * cq + j];
    }
    int ntiles = (N + 63) >> 6;
    for (int tile = blockIdx.x; tile < ntiles; tile += gridDim.x) {
        int r0 = tile << 6;
        float acc[4][4];
        #pragma unroll
        for (int i = 0; i < 4; i++)
            #pragma unroll
            for (int j = 0; j < 4; j++) acc[i][j] = 0.f;
        for (int kc = 0; kc < 128; kc += 64) {
            __syncthreads();
            int srow = t >> 4, sf4 = t & 15;
            #pragma unroll
            for (int p = 0; p < 4; p++) {
                int r = r0 + srow + 16 * p;
                float4 v = make_float4(0.f, 0.f, 0.f, 0.f);
                if (r < N) v = *(const float4*)(x + (size_t)r * 128 + kc + 4 * sf4);
                *(float4*)&xs[srow + 16 * p][4 * sf4] = v;
            }
            __syncthreads();
            #pragma unroll 4
            for (int k = 0; k < 64; k++) {
                float4 bv = *(float4*)&Bs[(kc + k) * 64 + 4 * ct];
                #pragma unroll
                for (int i = 0; i < 4; i++) {
                    float xv = xs[4 * rt + i][k];
                    acc[i][0] = fmaf(xv, bv.x, acc[i][0]);
                    acc[i][1] = fmaf(xv, bv.y, acc[i][1]);
                    acc[i][2] = fmaf(xv, bv.z, acc[i][2]);
                    acc[i][3] = fmaf(xv, bv.w, acc[i][3]);
                }
            }
        }
        #pragma unroll
        for (int i = 0; i < 4; i++) {
            int r = r0 + 4 * rt + i;
            float ps = 0.f, pd = 0.f;
            #pragma unroll
            for (int j = 0; j < 4; j++) {
                ps = fmaf(acc[i][j], asv[j], ps);
                pd = fmaf(acc[i][j], adv[j], pd);
            }
            ps += __shfl_xor(ps, 1); ps += __shfl_xor(ps, 2);
            pd += __shfl_xor(pd, 1); pd += __shfl_xor(pd, 2);
            if (r < N) {
                __half2 h0 = __floats2half2_rn(acc[i][0], acc[i][1]);
                __half2 h1 = __floats2half2_rn(acc[i][2], acc[i][3]);
                *(__half2*)(h + (size_t)r * 64 + 4 * ct) = h0;
                *(__half2*)(h + (size_t)r * 64 + 4 * ct + 2) = h1;
                if (cq == 0) { alsrc[r * 4 + head] = ps; aldst[r * 4 + head] = pd; }
            }
        }
    }
}

// ---------------- Layer 1 node aggregation: quarter-wave per node, 4-deep edge pipeline ----------------

__global__ __launch_bounds__(256) void node1_k(const __half* __restrict__ h, const int* __restrict__ srccol,
                                               const float* __restrict__ alsrc, const float* __restrict__ aldst,
                                               const int* __restrict__ rp, const int* __restrict__ cnt,
                                               const float* __restrict__ bias, __half* __restrict__ out, int N) {
    int t = threadIdx.x;
    int d = (blockIdx.x * 256 + t) >> 4;
    if (d >= N) return;
    int c = t & 15;
    int hc = c >> 2;
    const __half2* hb = (const __half2*)h;
    unsigned co = 2u * c;
    float ad = aldst[d * 4 + hc];
    float e = alsrc[d * 4 + hc] + ad;
    float w = WEXP(e);
    float den = w;
    __half2 wp = __float2half2_rn(w);
    uint2 u = *(const uint2*)(hb + ((unsigned)d << 5) + co);
    __half2 acc0 = __hmul2(wp, *(__half2*)&u.x);
    __half2 acc1 = __hmul2(wp, *(__half2*)&u.y);
    int start = rp[d], deg = cnt[d];
    int i = 0;
    for (; i + 3 < deg; i += 4) {
        int s0 = srccol[start + i];
        int s1 = srccol[start + i + 1];
        int s2 = srccol[start + i + 2];
        int s3 = srccol[start + i + 3];
        uint2 u0 = *(const uint2*)(hb + ((unsigned)s0 << 5) + co);
        uint2 u1 = *(const uint2*)(hb + ((unsigned)s1 << 5) + co);
        uint2 u2 = *(const uint2*)(hb + ((unsigned)s2 << 5) + co);
        uint2 u3 = *(const uint2*)(hb + ((unsigned)s3 << 5) + co);
        float e0 = alsrc[s0 * 4 + hc] + ad;
        float e1 = alsrc[s1 * 4 + hc] + ad;
        float e2 = alsrc[s2 * 4 + hc] + ad;
        float e3 = alsrc[s3 * 4 + hc] + ad;
        float w0 = WEXP(e0);
        float w1 = WEXP(e1);
        float w2 = WEXP(e2);
        float w3 = WEXP(e3);
        den += (w0 + w1) + (w2 + w3);
        __half2 p0 = __float2half2_rn(w0), p1 = __float2half2_rn(w1);
        __half2 p2 = __float2half2_rn(w2), p3 = __float2half2_rn(w3);
        acc0 = __hfma2(p0, *(__half2*)&u0.x, acc0);
        acc1 = __hfma2(p0, *(__half2*)&u0.y, acc1);
        acc0 = __hfma2(p1, *(__half2*)&u1.x, acc0);
        acc1 = __hfma2(p1, *(__half2*)&u1.y, acc1);
        acc0 = __hfma2(p2, *(__half2*)&u2.x, acc0);
        acc1 = __hfma2(p2, *(__half2*)&u2.y, acc1);
        acc0 = __hfma2(p3, *(__half2*)&u3.x, acc0);
        acc1 = __hfma2(p3, *(__half2*)&u3.y, acc1);
    }
    for (; i < deg; i++) {
        int s = srccol[start + i];
        uint2 us = *(const uint2*)(hb + ((unsigned)s << 5) + co);
        float es = alsrc[s * 4 + hc] + ad;
        float ws = WEXP(es);
        den += ws;
        __half2 wps = __float2half2_rn(ws);
        acc0 = __hfma2(wps, *(__half2*)&us.x, acc0);
        acc1 = __hfma2(wps, *(__half2*)&us.y, acc1);
    }
    float inv = 1.f / den;
    float2 f0 = __half22float2(acc0), f1 = __half22float2(acc1);
    float4 b = *(const float4*)(bias + 4 * c);
    __half2 o0 = __floats2half2_rn(f0.x * inv + b.x, f0.y * inv + b.y);
    __half2 o1 = __floats2half2_rn(f1.x * inv + b.z, f1.y * inv + b.w);
    uint2 o; o.x = *(unsigned*)&o0; o.y = *(unsigned*)&o1;
    *(uint2*)(out + (size_t)d * 64 + 4 * c) = o;
}

// ---------------- Folded attention-logit weights: w_as[k][h] = sum_c W2[k, h*32+c]*a_src2[h,c] ----------------

__global__ __launch_bounds__(256) void prew_k(const float* __restrict__ W2, const float* __restrict__ as2,
                                              const float* __restrict__ ad2, float* __restrict__ was,
                                              float* __restrict__ wad) {
    int t = threadIdx.x;          // t = k*4 + h, k in [0,64), h in [0,4)
    int k = t >> 2, hh = t & 3;
    const float* wrow = W2 + k * 128 + hh * 32;
    const float* av = as2 + hh * 32;
    const float* dv = ad2 + hh * 32;
    float s = 0.f, ds = 0.f;
    #pragma unroll 8
    for (int c = 0; c < 32; c++) {
        float w = wrow[c];
        s = fmaf(w, av[c], s);
        ds = fmaf(w, dv[c], ds);
    }
    was[t] = s;
    wad[t] = ds;
}

// ---------------- alv2: alsrc2[d,h] = h1o[d,:] . w_as[:,h] (quarter-wave per node) ----------------

__global__ __launch_bounds__(256) void alv2_k(const __half* __restrict__ h1o, const float* __restrict__ was,
                                              const float* __restrict__ wad, float* __restrict__ alsrc,
                                              float* __restrict__ aldst, int N) {
    int t = threadIdx.x;
    int d = (blockIdx.x * 256 + t) >> 4;
    if (d >= N) return;
    int c = t & 15;                       // lane owns dims 4c..4c+3
    uint2 u = *(const uint2*)(h1o + (size_t)d * 64 + 4 * c);
    float2 f0 = __half22float2(*(__half2*)&u.x);
    float2 f1 = __half22float2(*(__half2*)&u.y);
    float v0 = f0.x, v1 = f0.y, v2 = f1.x, v3 = f1.y;
    const float4* was4 = (const float4*)was;
    const float4* wad4 = (const float4*)wad;
    float4 wa0 = was4[4 * c + 0], wa1 = was4[4 * c + 1], wa2 = was4[4 * c + 2], wa3 = was4[4 * c + 3];
    float4 wd0 = wad4[4 * c + 0], wd1 = wad4[4 * c + 1], wd2 = wad4[4 * c + 2], wd3 = wad4[4 * c + 3];
    float4 ps, pd;
    ps.x = fmaf(v0, wa0.x, fmaf(v1, wa1.x, fmaf(v2, wa2.x, v3 * wa3.x)));
    ps.y = fmaf(v0, wa0.y, fmaf(v1, wa1.y, fmaf(v2, wa2.y, v3 * wa3.y)));
    ps.z = fmaf(v0, wa0.z, fmaf(v1, wa1.z, fmaf(v2, wa2.z, v3 * wa3.z)));
    ps.w = fmaf(v0, wa0.w, fmaf(v1, wa1.w, fmaf(v2, wa2.w, v3 * wa3.w)));
    pd.x = fmaf(v0, wd0.x, fmaf(v1, wd1.x, fmaf(v2, wd2.x, v3 * wd3.x)));
    pd.y = fmaf(v0, wd0.y, fmaf(v1, wd1.y, fmaf(v2, wd2.y, v3 * wd3.y)));
    pd.z = fmaf(v0, wd0.z, fmaf(v1, wd1.z, fmaf(v2, wd2.z, v3 * wd3.z)));
    pd.w = fmaf(v0, wd0.w, fmaf(v1, wd1.w, fmaf(v2, wd2.w, v3 * wd3.w)));
    #pragma unroll
    for (int off = 1; off <= 8; off <<= 1) {
        ps.x += __shfl_xor(ps.x, off); ps.y += __shfl_xor(ps.y, off);
        ps.z += __shfl_xor(ps.z, off); ps.w += __shfl_xor(ps.w, off);
        pd.x += __shfl_xor(pd.x, off); pd.y += __shfl_xor(pd.y, off);
        pd.z += __shfl_xor(pd.z, off); pd.w += __shfl_xor(pd.w, off);
    }
    if (c == 0) {
        *(float4*)(alsrc + (size_t)d * 4) = ps;
        *(float4*)(aldst + (size_t)d * 4) = pd;
    }
}

// ---------------- Layer 2 node aggregation over h1o: lane owns dims 4c..4c+3 for ALL 4 heads ----------------
// Row read exactly once per node-group (8B/lane). Each lane computes all 4 head weights (redundant VALU,
// cheap) and keeps 4 dens + 8 half2 accs. y[d, h*64+k] = z_h[d,k] * 0.25/den_h.

#define EDGE2(U, F) { \
    float wa = WEXP(F.x + ad4.x), wb = WEXP(F.y + ad4.y); \
    float wc = WEXP(F.z + ad4.z), wd = WEXP(F.w + ad4.w); \
    dnA += wa; dnB += wb; dnC += wc; dnD += wd; \
    __half2 l = *(__half2*)&U.x, hh = *(__half2*)&U.y; \
    __half2 qa = __float2half2_rn(wa), qb = __float2half2_rn(wb); \
    __half2 qc = __float2half2_rn(wc), qd = __float2half2_rn(wd); \
    aA0 = __hfma2(qa, l, aA0); aA1 = __hfma2(qa, hh, aA1); \
    aB0 = __hfma2(qb, l, aB0); aB1 = __hfma2(qb, hh, aB1); \
    aC0 = __hfma2(qc, l, aC0); aC1 = __hfma2(qc, hh, aC1); \
    aD0 = __hfma2(qd, l, aD0); aD1 = __hfma2(qd, hh, aD1); }

__global__ __launch_bounds__(256) void node2_k(const __half* __restrict__ h1o, const int* __restrict__ srccol,
                                               const float* __restrict__ alsrc, const float* __restrict__ aldst,
                                               const int* __restrict__ rp, const int* __restrict__ cnt,
                                               __half* __restrict__ y, int N) {
    int t = threadIdx.x;
    int d = (blockIdx.x * 256 + t) >> 4;
    if (d >= N) return;
    int c = t & 15;
    const uint2* hb = (const uint2*)h1o;           // 16 uint2 per 64-half row
    float4 ad4 = *(const float4*)(aldst + 4 * (size_t)d);
    float4 e4  = *(const float4*)(alsrc + 4 * (size_t)d);
    float wA = WEXP(e4.x + ad4.x);
    float wB = WEXP(e4.y + ad4.y);
    float wC = WEXP(e4.z + ad4.z);
    float wD = WEXP(e4.w + ad4.w);
    float dnA = wA, dnB = wB, dnC = wC, dnD = wD;
    uint2 u = hb[((size_t)d << 4) + c];
    __half2 lo = *(__half2*)&u.x, hi = *(__half2*)&u.y;
    __half2 pA = __float2half2_rn(wA), pB = __float2half2_rn(wB);
    __half2 pC = __float2half2_rn(wC), pD = __float2half2_rn(wD);
    __half2 aA0 = __hmul2(pA, lo), aA1 = __hmul2(pA, hi);
    __half2 aB0 = __hmul2(pB, lo), aB1 = __hmul2(pB, hi);
    __half2 aC0 = __hmul2(pC, lo), aC1 = __hmul2(pC, hi);
    __half2 aD0 = __hmul2(pD, lo), aD1 = __hmul2(pD, hi);
    int start = rp[d], deg = cnt[d];
    int i = 0;
    for (; i + 3 < deg; i += 4) {
        int s0 = srccol[start + i];
        int s1 = srccol[start + i + 1];
        int s2 = srccol[start + i + 2];
        int s3 = srccol[start + i + 3];
        uint2 u0 = hb[((size_t)s0 << 4) + c];
        uint2 u1 = hb[((size_t)s1 << 4) + c];
        uint2 u2 = hb[((size_t)s2 << 4) + c];
        uint2 u3 = hb[((size_t)s3 << 4) + c];
        float4 f0 = *(const float4*)(alsrc + 4 * (size_t)s0);
        float4 f1 = *(const float4*)(alsrc + 4 * (size_t)s1);
        float4 f2 = *(const float4*)(alsrc + 4 * (size_t)s2);
        float4 f3 = *(const float4*)(alsrc + 4 * (size_t)s3);
        EDGE2(u0, f0)
        EDGE2(u1, f1)
        EDGE2(u2, f2)
        EDGE2(u3, f3)
    }
    for (; i < deg; i++) {
        int s = srccol[start + i];
        uint2 us = hb[((size_t)s << 4) + c];
        float4 fs = *(const float4*)(alsrc + 4 * (size_t)s);
        EDGE2(us, fs)
    }
    float ivA = 0.25f / dnA, ivB = 0.25f / dnB, ivC = 0.25f / dnC, ivD = 0.25f / dnD;
    __half2 jA = __float2half2_rn(ivA), jB = __float2half2_rn(ivB);
    __half2 jC = __float2half2_rn(ivC), jD = __float2half2_rn(ivD);
    uint2 oA, oB, oC, oD;
    ((__half2*)&oA)[0] = __hmul2(jA, aA0); ((__half2*)&oA)[1] = __hmul2(jA, aA1);
    ((__half2*)&oB)[0] = __hmul2(jB, aB0); ((__half2*)&oB)[1] = __hmul2(jB, aB1);
    ((__half2*)&oC)[0] = __hmul2(jC, aC0); ((__half2*)&oC)[1] = __hmul2(jC, aC1);
    ((__half2*)&oD)[0] = __hmul2(jD, aD0); ((__half2*)&oD)[1] = __hmul2(jD, aD1);
    __half* yp = y + (size_t)d * 256 + 4u * (unsigned)c;
    *(uint2*)(yp)       = oA;
    *(uint2*)(yp + 64)  = oB;
    *(uint2*)(yp + 128) = oC;
    *(uint2*)(yp + 192) = oD;
}

// ---------------- Final: out = logsoftmax(elu(y @ W2s + b2)) ; W2s[h*64+k][c] = W2[k][h*32+c] ----------------

__global__ __launch_bounds__(256) void gemm3_k(const __half* __restrict__ y, const float* __restrict__ W2,
                                               const float* __restrict__ bias, float* __restrict__ out, int N) {
    __shared__ __half2 ws[256 * 16];      // [k'][c2]: cols 2c2,2c2+1
    __shared__ __half2 ys[64 * 134];      // [row][k2], pad 134 (bank-spread, 8B aligned)
    int t = threadIdx.x;
    for (int i = t; i < 4096; i += 256) {
        int kp = i >> 4, c2 = i & 15;
        int hh = kp >> 6, kk = kp & 63;
        const float* wp = W2 + kk * 128 + hh * 32 + 2 * c2;
        ws[i] = __floats2half2_rn(wp[0], wp[1]);
    }
    int ct = t & 7, rt = t >> 3;          // cols 4ct..4ct+3; rows 2rt,2rt+1
    float4 b4 = *(const float4*)(bias + 4 * ct);
    int ntiles = (N + 63) >> 6;
    for (int tile = blockIdx.x; tile < ntiles; tile += gridDim.x) {
        int r0 = tile << 6;
        __syncthreads();
        for (int i = t; i < 64 * 64; i += 256) {
            int row = i >> 6, k4 = i & 63;
            uint2 v = make_uint2(0u, 0u);
            int r = r0 + row;
            if (r < N) v = *(const uint2*)(y + (size_t)r * 256 + 4 * k4);
            *(uint2*)&ys[row * 134 + 2 * k4] = v;
        }
        __syncthreads();
        float acc[2][4];
        #pragma unroll
        for (int r = 0; r < 2; r++)
            #pragma unroll
            for (int j = 0; j < 4; j++) acc[r][j] = 0.f;
        const __half2* yr0 = ys + (2 * rt) * 134;
        const __half2* yr1 = ys + (2 * rt + 1) * 134;
        #pragma unroll 4
        for (int k2 = 0; k2 < 128; k2++) {
            const __half2* wk0 = ws + (2 * k2) * 16;
            const __half2* wk1 = wk0 + 16;
            float2 wA0 = __half22float2(wk0[2 * ct]);
            float2 wA1 = __half22float2(wk0[2 * ct + 1]);
            float2 wB0 = __half22float2(wk1[2 * ct]);
            float2 wB1 = __half22float2(wk1[2 * ct + 1]);
            float2 xa = __half22float2(yr0[k2]);
            float2 xb = __half22float2(yr1[k2]);
            acc[0][0] = fmaf(xa.x, wA0.x, acc[0][0]); acc[0][1] = fmaf(xa.x, wA0.y, acc[0][1]);
            acc[0][2] = fmaf(xa.x, wA1.x, acc[0][2]); acc[0][3] = fmaf(xa.x, wA1.y, acc[0][3]);
            acc[0][0] = fmaf(xa.y, wB0.x, acc[0][0]); acc[0][1] = fmaf(xa.y, wB0.y, acc[0][1]);
            acc[0][2] = fmaf(xa.y, wB1.x, acc[0][2]); acc[0][3] = fmaf(xa.y, wB1.y, acc[0][3]);
            acc[1][0] = fmaf(xb.x, wA0.x, acc[1][0]); acc[1][1] = fmaf(xb.x, wA0.y, acc[1][1]);
            acc[1][2] = fmaf(xb.x, wA1.x, acc[1][2]); acc[1][3] = fmaf(xb.x, wA1.y, acc[1][3]);
            acc[1][0] = fmaf(xb.y, wB0.x, acc[1][0]); acc[1][1] = fmaf(xb.y, wB0.y, acc[1][1]);
            acc[1][2] = fmaf(xb.y, wB1.x, acc[1][2]); acc[1][3] = fmaf(xb.y, wB1.y, acc[1][3]);
        }
        #pragma unroll
        for (int r = 0; r < 2; r++) {
            int row = r0 + 2 * rt + r;
            float ev0 = acc[r][0] + b4.x;
            float ev1 = acc[r][1] + b4.y;
            float ev2 = acc[r][2] + b4.z;
            float ev3 = acc[r][3] + b4.w;
            ev0 = ev0 > 0.f ? ev0 : __expf(ev0) - 1.f;
            ev1 = ev1 > 0.f ? ev1 : __expf(ev1) - 1.f;
            ev2 = ev2 > 0.f ? ev2 : __expf(ev2) - 1.f;
            ev3 = ev3 > 0.f ? ev3 : __expf(ev3) - 1.f;
            float mx = fmaxf(fmaxf(ev0, ev1), fmaxf(ev2, ev3));
            #pragma unroll
            for (int off = 1; off <= 4; off <<= 1) mx = fmaxf(mx, __shfl_xor(mx, off));
            float sm = __expf(ev0 - mx) + __expf(ev1 - mx) + __expf(ev2 - mx) + __expf(ev3 - mx);
            #pragma unroll
            for (int off = 1; off <= 4; off <<= 1) sm += __shfl_xor(sm, off);
            float ls = mx + __logf(sm);
            if (row < N) {
                float4 o;
                o.x = ev0 - ls; o.y = ev1 - ls; o.z = ev2 - ls; o.w = ev3 - ls;
                *(float4*)(out + (size_t)row * 32 + 4 * ct) = o;
            }
        }
    }
}

// ---------------- launch ----------------

extern "C" void kernel_launch(void* const* d_in, const int* in_sizes, int n_in,
                              void* d_out, int out_size, void* d_ws, size_t ws_size,
                              hipStream_t stream) {
    const float* x   = (const float*)d_in[0];
    const int*   ei  = (const int*)d_in[1];
    const float* W1  = (const float*)d_in[2];
    const float* as1 = (const float*)d_in[3];
    const float* ad1 = (const float*)d_in[4];
    const float* b1  = (const float*)d_in[5];
    const float* W2  = (const float*)d_in[6];
    const float* as2 = (const float*)d_in[7];
    const float* ad2 = (const float*)d_in[8];
    const float* b2  = (const float*)d_in[9];
    float* out = (float*)d_out;
    int N = in_sizes[0] / 128;
    int E = in_sizes[1] / 2;

    char* base = (char*)d_ws;
    size_t off = 0;
    auto alloc = [&](size_t bytes) -> char* {
        char* p = base + off;
        off = (off + bytes + 255) & ~(size_t)255;
        return p;
    };
    // y [N,256] fp16 (51.2MB) overlays h1h [N,64] fp16 (dead after node1) and
    // pairs [E] uint2 (dead after partB2): both are fully consumed before node2 writes y.
    __half* y     = (__half*)alloc((size_t)N * 256 * 2);
    __half* h1h   = (__half*)y;
    uint2*  pairs = (uint2*)((char*)y + (size_t)N * 64 * 2);
    __half* h1o   = (__half*)alloc((size_t)N * 64 * 2);
    float* alsrc1 = (float*)alloc((size_t)N * 4 * 4);
    float* aldst1 = (float*)alloc((size_t)N * 4 * 4);
    float* alsrc2 = (float*)alloc((size_t)N * 4 * 4);
    float* aldst2 = (float*)alloc((size_t)N * 4 * 4);
    float* was    = (float*)alloc(256 * 4);
    float* wad    = (float*)alloc(256 * 4);
    int* cnt  = (int*)alloc((size_t)N * 4);
    int* rp   = (int*)alloc((size_t)N * 4);
    int* curA = (int*)alloc(256 * 4);
    int* bc   = (int*)alloc(256 * 4);
    int* bb   = (int*)alloc(260 * 4);
    int* srccol = (int*)alloc((size_t)E * 4);

    int nbk = (N + 511) >> 9;       // 512-node buckets
    int ntilesA = (E + TILE - 1) / TILE;

    prew_k<<<1, 256, 0, stream>>>(W2, as2, ad2, was, wad);
    hipMemsetAsync(bc, 0, 256 * 4, stream);
    bhist_k<<<512, 256, 0, stream>>>(ei, bc, E, nbk);
    bscan_k<<<1, 256, 0, stream>>>(bc, bb, curA, nbk);
    partA_k<<<ntilesA, 256, 0, stream>>>(ei, curA, pairs, E, nbk);
    partB2_k<<<nbk, 256, 0, stream>>>(pairs, bb, rp, cnt, srccol, N);

    gemm1_k<<<768, 256, 0, stream>>>(x, W1, as1, ad1, h1h, alsrc1, aldst1, N);
    node1_k<<<(N + 15) / 16, 256, 0, stream>>>(h1h, srccol, alsrc1, aldst1, rp, cnt, b1, h1o, N);
    alv2_k<<<(N + 15) / 16, 256, 0, stream>>>(h1o, was, wad, alsrc2, aldst2, N);
    node2_k<<<(N + 15) / 16, 256, 0, stream>>>(h1o, srccol, alsrc2, aldst2, rp, cnt, y, N);
    gemm3_k<<<768, 256, 0, stream>>>(y, W2, b2, out, N);
}

// Round 3
// 344.048 us; speedup vs baseline: 1.2025x; 1.0211x over previous
//
#include <hip/hip_runtime.h>
#include <hip/hip_fp16.h>
#include <cstdint>
#include <cstddef>

#define NEG 0.2f
#define TILE 4096   // edges per partition tile
#define WEXP(e) __expf((e) > 0.f ? (e) : NEG * (e))

typedef _Float16 fh2 __attribute__((ext_vector_type(2)));

__device__ __forceinline__ fh2 bfh2(unsigned v) { fh2 r; *(unsigned*)&r = v; return r; }
__device__ __forceinline__ __half2 bch(int v) { __half2 r; *(int*)&r = v; return r; }

#if __has_builtin(__builtin_amdgcn_fdot2)
#define FDOT2(a, b, c) __builtin_amdgcn_fdot2((a), (b), (c), false)
#else
__device__ __forceinline__ float FDOT2(fh2 a, fh2 b, float c) {
    return fmaf((float)a.x, (float)b.x, fmaf((float)a.y, (float)b.y, c));
}
#endif

// ---------------- Bucket histogram (LDS-privatized): bc[b] = #edges with dst in bucket b ----------------

__global__ __launch_bounds__(256) void bhist_k(const int* __restrict__ ei, int* __restrict__ bc, int E, int nbk) {
    __shared__ int sb[256];
    int t = threadIdx.x;
    sb[t] = 0;
    __syncthreads();
    int stride = gridDim.x * 256;
    for (int i = blockIdx.x * 256 + t; i < E; i += stride) {
        int d = __builtin_nontemporal_load(ei + E + i);
        atomicAdd(&sb[d >> 9], 1);
    }
    __syncthreads();
    if (t < nbk && sb[t] > 0) atomicAdd(&bc[t], sb[t]);
}

// ---------------- Bucket scan: bb[b] = exclusive scan of bc; curA[b] = bb[b]; bb[nbk] = E ----------------

__global__ __launch_bounds__(256) void bscan_k(const int* __restrict__ bc, int* __restrict__ bb,
                                               int* __restrict__ curA, int nbk) {
    __shared__ int sm[256];
    int t = threadIdx.x;
    int v = (t < nbk) ? bc[t] : 0;
    sm[t] = v; __syncthreads();
    for (int off = 1; off < 256; off <<= 1) {
        int u = (t >= off) ? sm[t - off] : 0;
        __syncthreads();
        sm[t] += u;
        __syncthreads();
    }
    if (t < nbk) {
        int ex = sm[t] - v;
        bb[t] = ex;
        curA[t] = ex;
        if (t == nbk - 1) bb[nbk] = sm[t];
    }
}

// ---------------- Phase A: LDS-staged partition of edges into 512-node buckets ----------------

__global__ __launch_bounds__(256) void partA_k(const int* __restrict__ ei, int* __restrict__ curA,
                                               uint2* __restrict__ pairs, int E, int nbk) {
    __shared__ int scnt[256];
    __shared__ int sc[256];
    __shared__ int sbase[256];
    __shared__ int gbase[256];
    __shared__ int cur2[256];
    __shared__ int ssrc[TILE];
    __shared__ int sdst[TILE];
    int t = threadIdx.x;
    int ntiles = (E + TILE - 1) / TILE;
    for (int tile = blockIdx.x; tile < ntiles; tile += gridDim.x) {
        int base = tile * TILE;
        int cntE = min(TILE, E - base);
        scnt[t] = 0;
        __syncthreads();
        int mys[16], myd[16];
        #pragma unroll
        for (int j = 0; j < 16; j++) {
            int i = base + t + 256 * j;
            int s = 0, d = -1;
            if (i < E) {
                s = __builtin_nontemporal_load(ei + i);
                d = __builtin_nontemporal_load(ei + E + i);
            }
            mys[j] = s; myd[j] = d;
            if (d >= 0) atomicAdd(&scnt[d >> 9], 1);
        }
        __syncthreads();
        sc[t] = scnt[t];
        __syncthreads();
        for (int off = 1; off < 256; off <<= 1) {
            int u = (t >= off) ? sc[t - off] : 0;
            __syncthreads();
            sc[t] += u;
            __syncthreads();
        }
        int myb = sc[t] - scnt[t];
        sbase[t] = myb;
        cur2[t] = myb;
        if (t < nbk && scnt[t] > 0) gbase[t] = atomicAdd(&curA[t], scnt[t]);
        __syncthreads();
        #pragma unroll
        for (int j = 0; j < 16; j++) {
            int d = myd[j];
            if (d >= 0) {
                int b = d >> 9;
                int pos = atomicAdd(&cur2[b], 1);
                ssrc[pos] = mys[j];
                sdst[pos] = d;
            }
        }
        __syncthreads();
        for (int i = t; i < cntE; i += 256) {
            int d = sdst[i];
            int b = d >> 9;
            int addr = gbase[b] + (i - sbase[b]);
            pairs[addr] = make_uint2((unsigned)ssrc[i], (unsigned)d);
        }
        __syncthreads();
    }
}

// ---------------- Phase B (two-pass): per-node count + scan -> rp/cnt, then scatter ----------------

__global__ __launch_bounds__(256) void partB2_k(const uint2* __restrict__ pin, const int* __restrict__ bb,
                                                int* __restrict__ rp, int* __restrict__ cnt,
                                                int* __restrict__ srcout, int N) {
    __shared__ int cur[512];
    __shared__ int sc[512];
    int b = blockIdx.x, t = threadIdx.x;
    int d0 = b << 9;
    cur[t] = 0; cur[t + 256] = 0;
    __syncthreads();
    int ebase = bb[b], eend = bb[b + 1];
    for (int j = ebase + t; j < eend; j += 256) {
        int d = (int)pin[j].y;
        atomicAdd(&cur[d - d0], 1);
    }
    __syncthreads();
    sc[t] = cur[t]; sc[t + 256] = cur[t + 256];
    __syncthreads();
    for (int off = 1; off <= 256; off <<= 1) {
        int a0 = (t >= off) ? sc[t - off] : 0;
        int a1 = sc[t + 256 - off];
        __syncthreads();
        sc[t] += a0; sc[t + 256] += a1;
        __syncthreads();
    }
    // sc = inclusive scan; node base = ebase + sc - cur
    int base0 = ebase + sc[t] - cur[t];
    int base1 = ebase + sc[t + 256] - cur[t + 256];
    if (d0 + t < N)       { rp[d0 + t] = base0;       cnt[d0 + t] = cur[t]; }
    if (d0 + t + 256 < N) { rp[d0 + t + 256] = base1; cnt[d0 + t + 256] = cur[t + 256]; }
    cur[t] = base0; cur[t + 256] = base1;
    __syncthreads();
    for (int j = ebase + t; j < eend; j += 256) {
        uint2 p = pin[j];
        int d = (int)p.y;
        int pos = atomicAdd(&cur[d - d0], 1);
        srcout[pos] = (int)p.x;
    }
}

// ---------------- Layer 1 GEMM: h1 = x @ W1 (fp16 out), register-tiled ----------------

__global__ __launch_bounds__(256) void gemm1_k(const float* __restrict__ x, const float* __restrict__ W,
                                               const float* __restrict__ a_src, const float* __restrict__ a_dst,
                                               __half* __restrict__ h, float* __restrict__ alsrc,
                                               float* __restrict__ aldst, int N) {
    __shared__ float Bs[128 * 64];
    __shared__ float xs[64][68];
    int t = threadIdx.x;
    for (int i = t; i < 128 * 64 / 4; i += 256)
        ((float4*)Bs)[i] = ((const float4*)W)[i];
    int ct = t & 15, rt = t >> 4;
    int head = ct >> 2, cq = ct & 3;
    float asv[4], adv[4];
    #pragma unroll
    for (int j = 0; j < 4; j++) {
        asv[j] = a_src[head * 16 + 4 * cq + j];
        adv[j] = a_dst[head * 16 + 4 * cq + j];
    }
    int ntiles = (N + 63) >> 6;
    for (int tile = blockIdx.x; tile < ntiles; tile += gridDim.x) {
        int r0 = tile << 6;
        float acc[4][4];
        #pragma unroll
        for (int i = 0; i < 4; i++)
            #pragma unroll
            for (int j = 0; j < 4; j++) acc[i][j] = 0.f;
        for (int kc = 0; kc < 128; kc += 64) {
            __syncthreads();
            int srow = t >> 4, sf4 = t & 15;
            #pragma unroll
            for (int p = 0; p < 4; p++) {
                int r = r0 + srow + 16 * p;
                float4 v = make_float4(0.f, 0.f, 0.f, 0.f);
                if (r < N) v = *(const float4*)(x + (size_t)r * 128 + kc + 4 * sf4);
                *(float4*)&xs[srow + 16 * p][4 * sf4] = v;
            }
            __syncthreads();
            #pragma unroll 4
            for (int k = 0; k < 64; k++) {
                float4 bv = *(float4*)&Bs[(kc + k) * 64 + 4 * ct];
                #pragma unroll
                for (int i = 0; i < 4; i++) {
                    float xv = xs[4 * rt + i][k];
                    acc[i][0] = fmaf(xv, bv.x, acc[i][0]);
                    acc[i][1] = fmaf(xv, bv.y, acc[i][1]);
                    acc[i][2] = fmaf(xv, bv.z, acc[i][2]);
                    acc[i][3] = fmaf(xv, bv.w, acc[i][3]);
                }
            }
        }
        #pragma unroll
        for (int i = 0; i < 4; i++) {
            int r = r0 + 4 * rt + i;
            float ps = 0.f, pd = 0.f;
            #pragma unroll
            for (int j = 0; j < 4; j++) {
                ps = fmaf(acc[i][j], asv[j], ps);
                pd = fmaf(acc[i][j], adv[j], pd);
            }
            ps += __shfl_xor(ps, 1); ps += __shfl_xor(ps, 2);
            pd += __shfl_xor(pd, 1); pd += __shfl_xor(pd, 2);
            if (r < N) {
                __half2 h0 = __floats2half2_rn(acc[i][0], acc[i][1]);
                __half2 h1 = __floats2half2_rn(acc[i][2], acc[i][3]);
                *(__half2*)(h + (size_t)r * 64 + 4 * ct) = h0;
                *(__half2*)(h + (size_t)r * 64 + 4 * ct + 2) = h1;
                if (cq == 0) { alsrc[r * 4 + head] = ps; aldst[r * 4 + head] = pd; }
            }
        }
    }
}

// ---------------- Layer 1 node aggregation: quarter-wave per node, 4-deep edge pipeline ----------------

__global__ __launch_bounds__(256) void node1_k(const __half* __restrict__ h, const int* __restrict__ srccol,
                                               const float* __restrict__ alsrc, const float* __restrict__ aldst,
                                               const int* __restrict__ rp, const int* __restrict__ cnt,
                                               const float* __restrict__ bias, __half* __restrict__ out, int N) {
    int t = threadIdx.x;
    int d = (blockIdx.x * 256 + t) >> 4;
    if (d >= N) return;
    int c = t & 15;
    int hc = c >> 2;
    const __half2* hb = (const __half2*)h;
    unsigned co = 2u * c;
    float ad = aldst[d * 4 + hc];
    float e = alsrc[d * 4 + hc] + ad;
    float w = WEXP(e);
    float den = w;
    __half2 wp = __float2half2_rn(w);
    uint2 u = *(const uint2*)(hb + ((unsigned)d << 5) + co);
    __half2 acc0 = __hmul2(wp, *(__half2*)&u.x);
    __half2 acc1 = __hmul2(wp, *(__half2*)&u.y);
    int start = rp[d], deg = cnt[d];
    int i = 0;
    for (; i + 3 < deg; i += 4) {
        int s0 = srccol[start + i];
        int s1 = srccol[start + i + 1];
        int s2 = srccol[start + i + 2];
        int s3 = srccol[start + i + 3];
        uint2 u0 = *(const uint2*)(hb + ((unsigned)s0 << 5) + co);
        uint2 u1 = *(const uint2*)(hb + ((unsigned)s1 << 5) + co);
        uint2 u2 = *(const uint2*)(hb + ((unsigned)s2 << 5) + co);
        uint2 u3 = *(const uint2*)(hb + ((unsigned)s3 << 5) + co);
        float e0 = alsrc[s0 * 4 + hc] + ad;
        float e1 = alsrc[s1 * 4 + hc] + ad;
        float e2 = alsrc[s2 * 4 + hc] + ad;
        float e3 = alsrc[s3 * 4 + hc] + ad;
        float w0 = WEXP(e0);
        float w1 = WEXP(e1);
        float w2 = WEXP(e2);
        float w3 = WEXP(e3);
        den += (w0 + w1) + (w2 + w3);
        __half2 p0 = __float2half2_rn(w0), p1 = __float2half2_rn(w1);
        __half2 p2 = __float2half2_rn(w2), p3 = __float2half2_rn(w3);
        acc0 = __hfma2(p0, *(__half2*)&u0.x, acc0);
        acc1 = __hfma2(p0, *(__half2*)&u0.y, acc1);
        acc0 = __hfma2(p1, *(__half2*)&u1.x, acc0);
        acc1 = __hfma2(p1, *(__half2*)&u1.y, acc1);
        acc0 = __hfma2(p2, *(__half2*)&u2.x, acc0);
        acc1 = __hfma2(p2, *(__half2*)&u2.y, acc1);
        acc0 = __hfma2(p3, *(__half2*)&u3.x, acc0);
        acc1 = __hfma2(p3, *(__half2*)&u3.y, acc1);
    }
    for (; i < deg; i++) {
        int s = srccol[start + i];
        uint2 us = *(const uint2*)(hb + ((unsigned)s << 5) + co);
        float es = alsrc[s * 4 + hc] + ad;
        float ws = WEXP(es);
        den += ws;
        __half2 wps = __float2half2_rn(ws);
        acc0 = __hfma2(wps, *(__half2*)&us.x, acc0);
        acc1 = __hfma2(wps, *(__half2*)&us.y, acc1);
    }
    float inv = 1.f / den;
    float2 f0 = __half22float2(acc0), f1 = __half22float2(acc1);
    float4 b = *(const float4*)(bias + 4 * c);
    __half2 o0 = __floats2half2_rn(f0.x * inv + b.x, f0.y * inv + b.y);
    __half2 o1 = __floats2half2_rn(f1.x * inv + b.z, f1.y * inv + b.w);
    uint2 o; o.x = *(unsigned*)&o0; o.y = *(unsigned*)&o1;
    *(uint2*)(out + (size_t)d * 64 + 4 * c) = o;
}

// ---------------- Folded attention-logit weights: w_as[k][h] = sum_c W2[k, h*32+c]*a_src2[h,c] ----------------

__global__ __launch_bounds__(256) void prew_k(const float* __restrict__ W2, const float* __restrict__ as2,
                                              const float* __restrict__ ad2, float* __restrict__ was,
                                              float* __restrict__ wad) {
    int t = threadIdx.x;          // t = k*4 + h, k in [0,64), h in [0,4)
    int k = t >> 2, hh = t & 3;
    const float* wrow = W2 + k * 128 + hh * 32;
    const float* av = as2 + hh * 32;
    const float* dv = ad2 + hh * 32;
    float s = 0.f, ds = 0.f;
    #pragma unroll 8
    for (int c = 0; c < 32; c++) {
        float w = wrow[c];
        s = fmaf(w, av[c], s);
        ds = fmaf(w, dv[c], ds);
    }
    was[t] = s;
    wad[t] = ds;
}

// ---------------- alv2: alsrc2[d,h] = h1o[d,:] . w_as[:,h] (quarter-wave per node) ----------------

__global__ __launch_bounds__(256) void alv2_k(const __half* __restrict__ h1o, const float* __restrict__ was,
                                              const float* __restrict__ wad, float* __restrict__ alsrc,
                                              float* __restrict__ aldst, int N) {
    int t = threadIdx.x;
    int d = (blockIdx.x * 256 + t) >> 4;
    if (d >= N) return;
    int c = t & 15;                       // lane owns dims 4c..4c+3
    uint2 u = *(const uint2*)(h1o + (size_t)d * 64 + 4 * c);
    float2 f0 = __half22float2(*(__half2*)&u.x);
    float2 f1 = __half22float2(*(__half2*)&u.y);
    float v0 = f0.x, v1 = f0.y, v2 = f1.x, v3 = f1.y;
    const float4* was4 = (const float4*)was;
    const float4* wad4 = (const float4*)wad;
    float4 wa0 = was4[4 * c + 0], wa1 = was4[4 * c + 1], wa2 = was4[4 * c + 2], wa3 = was4[4 * c + 3];
    float4 wd0 = wad4[4 * c + 0], wd1 = wad4[4 * c + 1], wd2 = wad4[4 * c + 2], wd3 = wad4[4 * c + 3];
    float4 ps, pd;
    ps.x = fmaf(v0, wa0.x, fmaf(v1, wa1.x, fmaf(v2, wa2.x, v3 * wa3.x)));
    ps.y = fmaf(v0, wa0.y, fmaf(v1, wa1.y, fmaf(v2, wa2.y, v3 * wa3.y)));
    ps.z = fmaf(v0, wa0.z, fmaf(v1, wa1.z, fmaf(v2, wa2.z, v3 * wa3.z)));
    ps.w = fmaf(v0, wa0.w, fmaf(v1, wa1.w, fmaf(v2, wa2.w, v3 * wa3.w)));
    pd.x = fmaf(v0, wd0.x, fmaf(v1, wd1.x, fmaf(v2, wd2.x, v3 * wd3.x)));
    pd.y = fmaf(v0, wd0.y, fmaf(v1, wd1.y, fmaf(v2, wd2.y, v3 * wd3.y)));
    pd.z = fmaf(v0, wd0.z, fmaf(v1, wd1.z, fmaf(v2, wd2.z, v3 * wd3.z)));
    pd.w = fmaf(v0, wd0.w, fmaf(v1, wd1.w, fmaf(v2, wd2.w, v3 * wd3.w)));
    #pragma unroll
    for (int off = 1; off <= 8; off <<= 1) {
        ps.x += __shfl_xor(ps.x, off); ps.y += __shfl_xor(ps.y, off);
        ps.z += __shfl_xor(ps.z, off); ps.w += __shfl_xor(ps.w, off);
        pd.x += __shfl_xor(pd.x, off); pd.y += __shfl_xor(pd.y, off);
        pd.z += __shfl_xor(pd.z, off); pd.w += __shfl_xor(pd.w, off);
    }
    if (c == 0) {
        *(float4*)(alsrc + (size_t)d * 4) = ps;
        *(float4*)(aldst + (size_t)d * 4) = pd;
    }
}

// ---------------- Layer 2 node aggregation over h1o: lane owns dims 4c..4c+3 for ALL 4 heads ----------------
// Weight redundancy removed: lane c evaluates exactly ONE (edge c>>2, head c&3) weight per 4-edge
// block (1 exp + 1 cvt), then 16 shuffles broadcast the ready half2 multipliers to all lanes.
// Dens accumulate per-lane and are reduced with shfl_xor at the end.

#define EDGE_SH(J, U) { \
    __half2 l_ = *(__half2*)&U.x, h_ = *(__half2*)&U.y; \
    __half2 qa = bch(__shfl(wi, 4 * J + 0, 16)); \
    __half2 qb = bch(__shfl(wi, 4 * J + 1, 16)); \
    __half2 qc = bch(__shfl(wi, 4 * J + 2, 16)); \
    __half2 qd = bch(__shfl(wi, 4 * J + 3, 16)); \
    aA0 = __hfma2(qa, l_, aA0); aA1 = __hfma2(qa, h_, aA1); \
    aB0 = __hfma2(qb, l_, aB0); aB1 = __hfma2(qb, h_, aB1); \
    aC0 = __hfma2(qc, l_, aC0); aC1 = __hfma2(qc, h_, aC1); \
    aD0 = __hfma2(qd, l_, aD0); aD1 = __hfma2(qd, h_, aD1); }

__global__ __launch_bounds__(256) void node2_k(const __half* __restrict__ h1o, const int* __restrict__ srccol,
                                               const float* __restrict__ alsrc, const float* __restrict__ aldst,
                                               const int* __restrict__ rp, const int* __restrict__ cnt,
                                               __half* __restrict__ y, int N) {
    int t = threadIdx.x;
    int d = (blockIdx.x * 256 + t) >> 4;
    if (d >= N) return;
    int c = t & 15;
    int eh = c >> 2;      // edge slot this lane evaluates (0..3)
    int hh = c & 3;       // head this lane evaluates
    const uint2* hb = (const uint2*)h1o;           // 16 uint2 per 64-half row
    float myad = aldst[d * 4 + hh];
    // self-loop weight for head hh
    float selfw = WEXP(alsrc[d * 4 + hh] + myad);
    __half2 selfh = __float2half2_rn(selfw);
    int selfi = *(int*)&selfh;
    float mden = (eh == 0) ? selfw : 0.f;
    uint2 u = hb[((size_t)d << 4) + c];
    __half2 lo = *(__half2*)&u.x, hi = *(__half2*)&u.y;
    __half2 sA = bch(__shfl(selfi, 0, 16));
    __half2 sB = bch(__shfl(selfi, 1, 16));
    __half2 sC = bch(__shfl(selfi, 2, 16));
    __half2 sD = bch(__shfl(selfi, 3, 16));
    __half2 aA0 = __hmul2(sA, lo), aA1 = __hmul2(sA, hi);
    __half2 aB0 = __hmul2(sB, lo), aB1 = __hmul2(sB, hi);
    __half2 aC0 = __hmul2(sC, lo), aC1 = __hmul2(sC, hi);
    __half2 aD0 = __hmul2(sD, lo), aD1 = __hmul2(sD, hi);
    int start = rp[d], deg = cnt[d];
    int i = 0;
    for (; i + 3 < deg; i += 4) {
        int s0 = srccol[start + i];
        int s1 = srccol[start + i + 1];
        int s2 = srccol[start + i + 2];
        int s3 = srccol[start + i + 3];
        uint2 u0 = hb[((size_t)s0 << 4) + c];
        uint2 u1 = hb[((size_t)s1 << 4) + c];
        uint2 u2 = hb[((size_t)s2 << 4) + c];
        uint2 u3 = hb[((size_t)s3 << 4) + c];
        int my = (eh == 0) ? s0 : (eh == 1) ? s1 : (eh == 2) ? s2 : s3;
        float w = WEXP(alsrc[my * 4 + hh] + myad);
        mden += w;
        __half2 wh = __float2half2_rn(w);
        int wi = *(int*)&wh;
        EDGE_SH(0, u0)
        EDGE_SH(1, u1)
        EDGE_SH(2, u2)
        EDGE_SH(3, u3)
    }
    for (; i < deg; i++) {
        int s = srccol[start + i];
        uint2 us = hb[((size_t)s << 4) + c];
        float w = WEXP(alsrc[s * 4 + hh] + myad);
        mden += (eh == 0) ? w : 0.f;
        __half2 wh = __float2half2_rn(w);
        int wi = *(int*)&wh;
        EDGE_SH(0, us)
    }
    // reduce dens: lanes {hh, hh+4, hh+8, hh+12} hold partial sums for head hh
    mden += __shfl_xor(mden, 4, 16);
    mden += __shfl_xor(mden, 8, 16);
    float dnA = __shfl(mden, 0, 16);
    float dnB = __shfl(mden, 1, 16);
    float dnC = __shfl(mden, 2, 16);
    float dnD = __shfl(mden, 3, 16);
    __half2 jA = __float2half2_rn(0.25f / dnA), jB = __float2half2_rn(0.25f / dnB);
    __half2 jC = __float2half2_rn(0.25f / dnC), jD = __float2half2_rn(0.25f / dnD);
    uint2 oA, oB, oC, oD;
    ((__half2*)&oA)[0] = __hmul2(jA, aA0); ((__half2*)&oA)[1] = __hmul2(jA, aA1);
    ((__half2*)&oB)[0] = __hmul2(jB, aB0); ((__half2*)&oB)[1] = __hmul2(jB, aB1);
    ((__half2*)&oC)[0] = __hmul2(jC, aC0); ((__half2*)&oC)[1] = __hmul2(jC, aC1);
    ((__half2*)&oD)[0] = __hmul2(jD, aD0); ((__half2*)&oD)[1] = __hmul2(jD, aD1);
    __half* yp = y + (size_t)d * 256 + 4u * (unsigned)c;
    *(uint2*)(yp)       = oA;
    *(uint2*)(yp + 64)  = oB;
    *(uint2*)(yp + 128) = oC;
    *(uint2*)(yp + 192) = oD;
}

// ---------------- Final: out = logsoftmax(elu(y @ W2s + b2)); fp16 dot2 inner loop ----------------
// W2s[h*64+k][c] = W2[k][h*32+c].  wk[k2][col] = half2(W2s[2k2][col], W2s[2k2+1][col]).

__global__ __launch_bounds__(256) void gemm3_k(const __half* __restrict__ y, const float* __restrict__ W2,
                                               const float* __restrict__ bias, float* __restrict__ out, int N) {
    __shared__ unsigned wk[128 * 32];     // 16 KB: K-pair half2 per column
    __shared__ unsigned ys[64 * 130];     // 33.3 KB: [row][k2] half2, pad 130
    int t = threadIdx.x;
    for (int i = t; i < 4096; i += 256) {
        int k2 = i >> 5, col = i & 31;
        int hh = k2 >> 5, kk = (2 * k2) & 63;
        float f0 = W2[kk * 128 + hh * 32 + col];
        float f1 = W2[(kk + 1) * 128 + hh * 32 + col];
        __half2 hv = __floats2half2_rn(f0, f1);
        wk[i] = *(unsigned*)&hv;
    }
    int ct = t & 7, rt = t >> 3;          // cols 4ct..4ct+3; rows 2rt,2rt+1
    float4 b4 = *(const float4*)(bias + 4 * ct);
    int r0 = blockIdx.x << 6;
    for (int i = t; i < 64 * 64; i += 256) {
        int row = i >> 6, k4 = i & 63;
        uint2 v = make_uint2(0u, 0u);
        int r = r0 + row;
        if (r < N) v = *(const uint2*)(y + (size_t)r * 256 + 4 * k4);
        *(uint2*)&ys[row * 130 + 2 * k4] = v;
    }
    __syncthreads();
    float acc[2][4];
    #pragma unroll
    for (int r = 0; r < 2; r++)
        #pragma unroll
        for (int j = 0; j < 4; j++) acc[r][j] = 0.f;
    const unsigned* yr0 = ys + (2 * rt) * 130;
    const unsigned* yr1 = yr0 + 130;
    const unsigned* wp = wk + 4 * ct;
    #pragma unroll 8
    for (int k2 = 0; k2 < 128; k2++) {
        fh2 xa = bfh2(yr0[k2]);
        fh2 xb = bfh2(yr1[k2]);
        uint2 w01 = *(const uint2*)&wp[k2 * 32];
        uint2 w23 = *(const uint2*)&wp[k2 * 32 + 2];
        fh2 w0 = bfh2(w01.x), w1 = bfh2(w01.y), w2 = bfh2(w23.x), w3 = bfh2(w23.y);
        acc[0][0] = FDOT2(xa, w0, acc[0][0]);
        acc[0][1] = FDOT2(xa, w1, acc[0][1]);
        acc[0][2] = FDOT2(xa, w2, acc[0][2]);
        acc[0][3] = FDOT2(xa, w3, acc[0][3]);
        acc[1][0] = FDOT2(xb, w0, acc[1][0]);
        acc[1][1] = FDOT2(xb, w1, acc[1][1]);
        acc[1][2] = FDOT2(xb, w2, acc[1][2]);
        acc[1][3] = FDOT2(xb, w3, acc[1][3]);
    }
    #pragma unroll
    for (int r = 0; r < 2; r++) {
        int row = r0 + 2 * rt + r;
        float ev0 = acc[r][0] + b4.x;
        float ev1 = acc[r][1] + b4.y;
        float ev2 = acc[r][2] + b4.z;
        float ev3 = acc[r][3] + b4.w;
        ev0 = ev0 > 0.f ? ev0 : __expf(ev0) - 1.f;
        ev1 = ev1 > 0.f ? ev1 : __expf(ev1) - 1.f;
        ev2 = ev2 > 0.f ? ev2 : __expf(ev2) - 1.f;
        ev3 = ev3 > 0.f ? ev3 : __expf(ev3) - 1.f;
        float mx = fmaxf(fmaxf(ev0, ev1), fmaxf(ev2, ev3));
        #pragma unroll
        for (int off = 1; off <= 4; off <<= 1) mx = fmaxf(mx, __shfl_xor(mx, off));
        float sm = __expf(ev0 - mx) + __expf(ev1 - mx) + __expf(ev2 - mx) + __expf(ev3 - mx);
        #pragma unroll
        for (int off = 1; off <= 4; off <<= 1) sm += __shfl_xor(sm, off);
        float ls = mx + __logf(sm);
        if (row < N) {
            float4 o;
            o.x = ev0 - ls; o.y = ev1 - ls; o.z = ev2 - ls; o.w = ev3 - ls;
            *(float4*)(out + (size_t)row * 32 + 4 * ct) = o;
        }
    }
}

// ---------------- launch ----------------

extern "C" void kernel_launch(void* const* d_in, const int* in_sizes, int n_in,
                              void* d_out, int out_size, void* d_ws, size_t ws_size,
                              hipStream_t stream) {
    const float* x   = (const float*)d_in[0];
    const int*   ei  = (const int*)d_in[1];
    const float* W1  = (const float*)d_in[2];
    const float* as1 = (const float*)d_in[3];
    const float* ad1 = (const float*)d_in[4];
    const float* b1  = (const float*)d_in[5];
    const float* W2  = (const float*)d_in[6];
    const float* as2 = (const float*)d_in[7];
    const float* ad2 = (const float*)d_in[8];
    const float* b2  = (const float*)d_in[9];
    float* out = (float*)d_out;
    int N = in_sizes[0] / 128;
    int E = in_sizes[1] / 2;

    char* base = (char*)d_ws;
    size_t off = 0;
    auto alloc = [&](size_t bytes) -> char* {
        char* p = base + off;
        off = (off + bytes + 255) & ~(size_t)255;
        return p;
    };
    // y [N,256] fp16 (51.2MB) overlays h1h [N,64] fp16 (dead after node1) and
    // pairs [E] uint2 (dead after partB2): both are fully consumed before node2 writes y.
    __half* y     = (__half*)alloc((size_t)N * 256 * 2);
    __half* h1h   = (__half*)y;
    uint2*  pairs = (uint2*)((char*)y + (size_t)N * 64 * 2);
    __half* h1o   = (__half*)alloc((size_t)N * 64 * 2);
    float* alsrc1 = (float*)alloc((size_t)N * 4 * 4);
    float* aldst1 = (float*)alloc((size_t)N * 4 * 4);
    float* alsrc2 = (float*)alloc((size_t)N * 4 * 4);
    float* aldst2 = (float*)alloc((size_t)N * 4 * 4);
    float* was    = (float*)alloc(256 * 4);
    float* wad    = (float*)alloc(256 * 4);
    int* cnt  = (int*)alloc((size_t)N * 4);
    int* rp   = (int*)alloc((size_t)N * 4);
    int* curA = (int*)alloc(256 * 4);
    int* bc   = (int*)alloc(256 * 4);
    int* bb   = (int*)alloc(260 * 4);
    int* srccol = (int*)alloc((size_t)E * 4);

    int nbk = (N + 511) >> 9;       // 512-node buckets
    int ntilesA = (E + TILE - 1) / TILE;
    int nt1 = (N + 63) >> 6;        // 64-row GEMM tiles

    prew_k<<<1, 256, 0, stream>>>(W2, as2, ad2, was, wad);
    hipMemsetAsync(bc, 0, 256 * 4, stream);
    bhist_k<<<512, 256, 0, stream>>>(ei, bc, E, nbk);
    bscan_k<<<1, 256, 0, stream>>>(bc, bb, curA, nbk);
    partA_k<<<ntilesA, 256, 0, stream>>>(ei, curA, pairs, E, nbk);
    partB2_k<<<nbk, 256, 0, stream>>>(pairs, bb, rp, cnt, srccol, N);

    gemm1_k<<<(nt1 + 1) / 2, 256, 0, stream>>>(x, W1, as1, ad1, h1h, alsrc1, aldst1, N);
    node1_k<<<(N + 15) / 16, 256, 0, stream>>>(h1h, srccol, alsrc1, aldst1, rp, cnt, b1, h1o, N);
    alv2_k<<<(N + 15) / 16, 256, 0, stream>>>(h1o, was, wad, alsrc2, aldst2, N);
    node2_k<<<(N + 15) / 16, 256, 0, stream>>>(h1o, srccol, alsrc2, aldst2, rp, cnt, y, N);
    gemm3_k<<<nt1, 256, 0, stream>>>(y, W2, b2, out, N);
}

// Round 4
// 333.131 us; speedup vs baseline: 1.2419x; 1.0328x over previous
//
#include <hip/hip_runtime.h>
#include <hip/hip_fp16.h>
#include <cstdint>
#include <cstddef>

#define NEG 0.2f
#define TILE 4096   // edges per partition tile
#define WEXP(e) __expf((e) > 0.f ? (e) : NEG * (e))

typedef int i4v __attribute__((ext_vector_type(4)));

__device__ __forceinline__ i4v ld_i4(const int* p) {   // dword-aligned 16B load
    i4v r;
    __builtin_memcpy(&r, p, 16);
    return r;
}
__device__ __forceinline__ __half2 bch(unsigned v) { __half2 r; *(unsigned*)&r = v; return r; }
__device__ __forceinline__ __half2 bchi(int v) { __half2 r; *(int*)&r = v; return r; }

// ---------------- Bucket histogram (LDS-privatized): bc[b] = #edges with dst in bucket b ----------------

__global__ __launch_bounds__(256) void bhist_k(const int* __restrict__ ei, int* __restrict__ bc, int E, int nbk) {
    __shared__ int sb[256];
    int t = threadIdx.x;
    sb[t] = 0;
    __syncthreads();
    int stride = gridDim.x * 256;
    for (int i = blockIdx.x * 256 + t; i < E; i += stride) {
        int d = __builtin_nontemporal_load(ei + E + i);
        atomicAdd(&sb[d >> 9], 1);
    }
    __syncthreads();
    if (t < nbk && sb[t] > 0) atomicAdd(&bc[t], sb[t]);
}

// ---------------- Bucket scan: bb[b] = exclusive scan of bc; curA[b] = bb[b]; bb[nbk] = E ----------------

__global__ __launch_bounds__(256) void bscan_k(const int* __restrict__ bc, int* __restrict__ bb,
                                               int* __restrict__ curA, int nbk) {
    __shared__ int sm[256];
    int t = threadIdx.x;
    int v = (t < nbk) ? bc[t] : 0;
    sm[t] = v; __syncthreads();
    for (int off = 1; off < 256; off <<= 1) {
        int u = (t >= off) ? sm[t - off] : 0;
        __syncthreads();
        sm[t] += u;
        __syncthreads();
    }
    if (t < nbk) {
        int ex = sm[t] - v;
        bb[t] = ex;
        curA[t] = ex;
        if (t == nbk - 1) bb[nbk] = sm[t];
    }
}

// ---------------- Phase A: LDS-staged partition of edges into 512-node buckets ----------------

__global__ __launch_bounds__(256) void partA_k(const int* __restrict__ ei, int* __restrict__ curA,
                                               uint2* __restrict__ pairs, int E, int nbk) {
    __shared__ int scnt[256];
    __shared__ int sc[256];
    __shared__ int sbase[256];
    __shared__ int gbase[256];
    __shared__ int cur2[256];
    __shared__ int ssrc[TILE];
    __shared__ int sdst[TILE];
    int t = threadIdx.x;
    int ntiles = (E + TILE - 1) / TILE;
    for (int tile = blockIdx.x; tile < ntiles; tile += gridDim.x) {
        int base = tile * TILE;
        int cntE = min(TILE, E - base);
        scnt[t] = 0;
        __syncthreads();
        int mys[16], myd[16];
        #pragma unroll
        for (int j = 0; j < 16; j++) {
            int i = base + t + 256 * j;
            int s = 0, d = -1;
            if (i < E) {
                s = __builtin_nontemporal_load(ei + i);
                d = __builtin_nontemporal_load(ei + E + i);
            }
            mys[j] = s; myd[j] = d;
            if (d >= 0) atomicAdd(&scnt[d >> 9], 1);
        }
        __syncthreads();
        sc[t] = scnt[t];
        __syncthreads();
        for (int off = 1; off < 256; off <<= 1) {
            int u = (t >= off) ? sc[t - off] : 0;
            __syncthreads();
            sc[t] += u;
            __syncthreads();
        }
        int myb = sc[t] - scnt[t];
        sbase[t] = myb;
        cur2[t] = myb;
        if (t < nbk && scnt[t] > 0) gbase[t] = atomicAdd(&curA[t], scnt[t]);
        __syncthreads();
        #pragma unroll
        for (int j = 0; j < 16; j++) {
            int d = myd[j];
            if (d >= 0) {
                int b = d >> 9;
                int pos = atomicAdd(&cur2[b], 1);
                ssrc[pos] = mys[j];
                sdst[pos] = d;
            }
        }
        __syncthreads();
        for (int i = t; i < cntE; i += 256) {
            int d = sdst[i];
            int b = d >> 9;
            int addr = gbase[b] + (i - sbase[b]);
            pairs[addr] = make_uint2((unsigned)ssrc[i], (unsigned)d);
        }
        __syncthreads();
    }
}

// ---------------- Phase B (two-pass): per-node count + scan -> rp/cnt, then scatter ----------------

__global__ __launch_bounds__(256) void partB2_k(const uint2* __restrict__ pin, const int* __restrict__ bb,
                                                int* __restrict__ rp, int* __restrict__ cnt,
                                                int* __restrict__ srcout, int N) {
    __shared__ int cur[512];
    __shared__ int sc[512];
    int b = blockIdx.x, t = threadIdx.x;
    int d0 = b << 9;
    cur[t] = 0; cur[t + 256] = 0;
    __syncthreads();
    int ebase = bb[b], eend = bb[b + 1];
    for (int j = ebase + t; j < eend; j += 256) {
        int d = (int)pin[j].y;
        atomicAdd(&cur[d - d0], 1);
    }
    __syncthreads();
    sc[t] = cur[t]; sc[t + 256] = cur[t + 256];
    __syncthreads();
    for (int off = 1; off <= 256; off <<= 1) {
        int a0 = (t >= off) ? sc[t - off] : 0;
        int a1 = sc[t + 256 - off];
        __syncthreads();
        sc[t] += a0; sc[t + 256] += a1;
        __syncthreads();
    }
    // sc = inclusive scan; node base = ebase + sc - cur
    int base0 = ebase + sc[t] - cur[t];
    int base1 = ebase + sc[t + 256] - cur[t + 256];
    if (d0 + t < N)       { rp[d0 + t] = base0;       cnt[d0 + t] = cur[t]; }
    if (d0 + t + 256 < N) { rp[d0 + t + 256] = base1; cnt[d0 + t + 256] = cur[t + 256]; }
    cur[t] = base0; cur[t + 256] = base1;
    __syncthreads();
    for (int j = ebase + t; j < eend; j += 256) {
        uint2 p = pin[j];
        int d = (int)p.y;
        int pos = atomicAdd(&cur[d - d0], 1);
        srcout[pos] = (int)p.x;
    }
}

// ---------------- Layer 1 GEMM: h1 = x @ W1 (fp16 out), register-tiled ----------------

__global__ __launch_bounds__(256) void gemm1_k(const float* __restrict__ x, const float* __restrict__ W,
                                               const float* __restrict__ a_src, const float* __restrict__ a_dst,
                                               __half* __restrict__ h, float* __restrict__ alsrc,
                                               float* __restrict__ aldst, int N) {
    __shared__ float Bs[128 * 64];
    __shared__ float xs[64][68];
    int t = threadIdx.x;
    for (int i = t; i < 128 * 64 / 4; i += 256)
        ((float4*)Bs)[i] = ((const float4*)W)[i];
    int ct = t & 15, rt = t >> 4;
    int head = ct >> 2, cq = ct & 3;
    float asv[4], adv[4];
    #pragma unroll
    for (int j = 0; j < 4; j++) {
        asv[j] = a_src[head * 16 + 4 * cq + j];
        adv[j] = a_dst[head * 16 + 4 * cq + j];
    }
    int ntiles = (N + 63) >> 6;
    for (int tile = blockIdx.x; tile < ntiles; tile += gridDim.x) {
        int r0 = tile << 6;
        float acc[4][4];
        #pragma unroll
        for (int i = 0; i < 4; i++)
            #pragma unroll
            for (int j = 0; j < 4; j++) acc[i][j] = 0.f;
        for (int kc = 0; kc < 128; kc += 64) {
            __syncthreads();
            int srow = t >> 4, sf4 = t & 15;
            #pragma unroll
            for (int p = 0; p < 4; p++) {
                int r = r0 + srow + 16 * p;
                float4 v = make_float4(0.f, 0.f, 0.f, 0.f);
                if (r < N) v = *(const float4*)(x + (size_t)r * 128 + kc + 4 * sf4);
                *(float4*)&xs[srow + 16 * p][4 * sf4] = v;
            }
            __syncthreads();
            #pragma unroll 4
            for (int k = 0; k < 64; k++) {
                float4 bv = *(float4*)&Bs[(kc + k) * 64 + 4 * ct];
                #pragma unroll
                for (int i = 0; i < 4; i++) {
                    float xv = xs[4 * rt + i][k];
                    acc[i][0] = fmaf(xv, bv.x, acc[i][0]);
                    acc[i][1] = fmaf(xv, bv.y, acc[i][1]);
                    acc[i][2] = fmaf(xv, bv.z, acc[i][2]);
                    acc[i][3] = fmaf(xv, bv.w, acc[i][3]);
                }
            }
        }
        #pragma unroll
        for (int i = 0; i < 4; i++) {
            int r = r0 + 4 * rt + i;
            float ps = 0.f, pd = 0.f;
            #pragma unroll
            for (int j = 0; j < 4; j++) {
                ps = fmaf(acc[i][j], asv[j], ps);
                pd = fmaf(acc[i][j], adv[j], pd);
            }
            ps += __shfl_xor(ps, 1); ps += __shfl_xor(ps, 2);
            pd += __shfl_xor(pd, 1); pd += __shfl_xor(pd, 2);
            if (r < N) {
                __half2 h0 = __floats2half2_rn(acc[i][0], acc[i][1]);
                __half2 h1 = __floats2half2_rn(acc[i][2], acc[i][3]);
                *(__half2*)(h + (size_t)r * 64 + 4 * ct) = h0;
                *(__half2*)(h + (size_t)r * 64 + 4 * ct + 2) = h1;
                if (cq == 0) { alsrc[r * 4 + head] = ps; aldst[r * 4 + head] = pd; }
            }
        }
    }
}

// ---------------- Folded attention-logit weights: w_as[k][h] = sum_c W2[k, h*32+c]*a_src2[h,c] ----------------

__global__ __launch_bounds__(256) void prew_k(const float* __restrict__ W2, const float* __restrict__ as2,
                                              const float* __restrict__ ad2, float* __restrict__ was,
                                              float* __restrict__ wad) {
    int t = threadIdx.x;          // t = k*4 + h, k in [0,64), h in [0,4)
    int k = t >> 2, hh = t & 3;
    const float* wrow = W2 + k * 128 + hh * 32;
    const float* av = as2 + hh * 32;
    const float* dv = ad2 + hh * 32;
    float s = 0.f, ds = 0.f;
    #pragma unroll 8
    for (int c = 0; c < 32; c++) {
        float w = wrow[c];
        s = fmaf(w, av[c], s);
        ds = fmaf(w, dv[c], ds);
    }
    was[t] = s;
    wad[t] = ds;
}

// ---------------- Layer 1 node aggregation + fused alv2 ----------------
// Lane c of each 16-lane node-group: owns h1 dims 4c..4c+3 (head mh=c>>2); evaluates the
// attention weight for (edge c>>2, head c&3) — 1 exp + 1 alsrc gather per 4-edge quad, then
// shuffles distribute ready-made half2 multipliers. srccol read as int4, software-pipelined
// one quad ahead (gathers issued one iteration before use). Epilogue computes alsrc2/aldst2
// (layer-2 attention logits) in-register — alv2 kernel eliminated.

__global__ __launch_bounds__(256) void node1_k(const __half* __restrict__ h, const int* __restrict__ srccol,
                                               const float* __restrict__ alsrc, const float* __restrict__ aldst,
                                               const int* __restrict__ rp, const int* __restrict__ cnt,
                                               const float* __restrict__ bias,
                                               const float* __restrict__ was, const float* __restrict__ wad,
                                               __half* __restrict__ out,
                                               float* __restrict__ alsrc2, float* __restrict__ aldst2, int N) {
    int t = threadIdx.x;
    int d = (blockIdx.x * 256 + t) >> 4;
    if (d >= N) return;
    int c = t & 15;
    int eh = c >> 2, hh = c & 3;   // lane evaluates (edge eh, head hh)
    int mh = c >> 2;               // lane's own dims belong to head mh
    const uint2* hb = (const uint2*)h;
    float myad = aldst[d * 4 + hh];
    float selfw = WEXP(alsrc[d * 4 + hh] + myad);
    __half2 sh2 = __float2half2_rn(selfw);
    int si = *(int*)&sh2;
    float mden = (eh == 0) ? selfw : 0.f;
    uint2 u = hb[((size_t)d << 4) + c];
    __half2 smy = bchi(__shfl(si, mh, 16));
    __half2 acc0 = __hmul2(smy, bch(u.x));
    __half2 acc1 = __hmul2(smy, bch(u.y));
    int start = rp[d], deg = cnt[d];
    int nq = deg >> 2;
    int i = 0;
    #define N1_PROC(G0, G1, G2, G3, AW) { \
        float w_ = WEXP((AW) + myad); \
        mden += w_; \
        __half2 wh_ = __float2half2_rn(w_); \
        int wi_ = *(int*)&wh_; \
        __half2 q0_ = bchi(__shfl(wi_, 0 + mh, 16)); \
        __half2 q1_ = bchi(__shfl(wi_, 4 + mh, 16)); \
        __half2 q2_ = bchi(__shfl(wi_, 8 + mh, 16)); \
        __half2 q3_ = bchi(__shfl(wi_, 12 + mh, 16)); \
        acc0 = __hfma2(q0_, bch(G0.x), acc0); acc1 = __hfma2(q0_, bch(G0.y), acc1); \
        acc0 = __hfma2(q1_, bch(G1.x), acc0); acc1 = __hfma2(q1_, bch(G1.y), acc1); \
        acc0 = __hfma2(q2_, bch(G2.x), acc0); acc1 = __hfma2(q2_, bch(G2.y), acc1); \
        acc0 = __hfma2(q3_, bch(G3.x), acc0); acc1 = __hfma2(q3_, bch(G3.y), acc1); }
    if (nq > 0) {
        i4v sv = ld_i4(srccol + start);
        uint2 g0 = hb[((size_t)(unsigned)sv.x << 4) + c];
        uint2 g1 = hb[((size_t)(unsigned)sv.y << 4) + c];
        uint2 g2 = hb[((size_t)(unsigned)sv.z << 4) + c];
        uint2 g3 = hb[((size_t)(unsigned)sv.w << 4) + c];
        int my = (eh == 0) ? sv.x : (eh == 1) ? sv.y : (eh == 2) ? sv.z : sv.w;
        float aw = alsrc[(size_t)my * 4 + hh];
        i4v nv = (nq > 1) ? ld_i4(srccol + start + 4) : sv;
        for (int q = 1; q < nq; q++) {
            uint2 n0 = hb[((size_t)(unsigned)nv.x << 4) + c];
            uint2 n1 = hb[((size_t)(unsigned)nv.y << 4) + c];
            uint2 n2 = hb[((size_t)(unsigned)nv.z << 4) + c];
            uint2 n3 = hb[((size_t)(unsigned)nv.w << 4) + c];
            int nmy = (eh == 0) ? nv.x : (eh == 1) ? nv.y : (eh == 2) ? nv.z : nv.w;
            float naw = alsrc[(size_t)nmy * 4 + hh];
            i4v nv2 = (q + 1 < nq) ? ld_i4(srccol + start + 4 * (q + 1)) : nv;
            N1_PROC(g0, g1, g2, g3, aw)
            g0 = n0; g1 = n1; g2 = n2; g3 = n3; aw = naw; nv = nv2;
        }
        N1_PROC(g0, g1, g2, g3, aw)
        i = nq << 2;
    }
    for (; i < deg; i++) {
        int s = srccol[start + i];
        uint2 us = hb[((size_t)(unsigned)s << 4) + c];
        float w = WEXP(alsrc[(size_t)s * 4 + hh] + myad);
        mden += (eh == 0) ? w : 0.f;
        __half2 wh = __float2half2_rn(w);
        int wi = *(int*)&wh;
        __half2 qq = bchi(__shfl(wi, mh, 16));
        acc0 = __hfma2(qq, bch(us.x), acc0);
        acc1 = __hfma2(qq, bch(us.y), acc1);
    }
    mden += __shfl_xor(mden, 4, 16);
    mden += __shfl_xor(mden, 8, 16);
    float den = __shfl(mden, mh, 16);
    float inv = 1.f / den;
    float2 f0 = __half22float2(acc0), f1 = __half22float2(acc1);
    float4 b = *(const float4*)(bias + 4 * c);
    float v0 = f0.x * inv + b.x, v1 = f0.y * inv + b.y;
    float v2 = f1.x * inv + b.z, v3 = f1.y * inv + b.w;
    __half2 o0 = __floats2half2_rn(v0, v1);
    __half2 o1 = __floats2half2_rn(v2, v3);
    uint2 o; o.x = *(unsigned*)&o0; o.y = *(unsigned*)&o1;
    *(uint2*)(out + (size_t)d * 64 + 4 * c) = o;
    // ---- fused alv2: alsrc2[d,h] = sum_k h1o[d,k]*was[k,h] ----
    const float4* was4 = (const float4*)was;
    const float4* wad4 = (const float4*)wad;
    float4 wa0 = was4[4 * c + 0], wa1 = was4[4 * c + 1], wa2 = was4[4 * c + 2], wa3 = was4[4 * c + 3];
    float4 wd0 = wad4[4 * c + 0], wd1 = wad4[4 * c + 1], wd2 = wad4[4 * c + 2], wd3 = wad4[4 * c + 3];
    float4 ps, pd;
    ps.x = fmaf(v0, wa0.x, fmaf(v1, wa1.x, fmaf(v2, wa2.x, v3 * wa3.x)));
    ps.y = fmaf(v0, wa0.y, fmaf(v1, wa1.y, fmaf(v2, wa2.y, v3 * wa3.y)));
    ps.z = fmaf(v0, wa0.z, fmaf(v1, wa1.z, fmaf(v2, wa2.z, v3 * wa3.z)));
    ps.w = fmaf(v0, wa0.w, fmaf(v1, wa1.w, fmaf(v2, wa2.w, v3 * wa3.w)));
    pd.x = fmaf(v0, wd0.x, fmaf(v1, wd1.x, fmaf(v2, wd2.x, v3 * wd3.x)));
    pd.y = fmaf(v0, wd0.y, fmaf(v1, wd1.y, fmaf(v2, wd2.y, v3 * wd3.y)));
    pd.z = fmaf(v0, wd0.z, fmaf(v1, wd1.z, fmaf(v2, wd2.z, v3 * wd3.z)));
    pd.w = fmaf(v0, wd0.w, fmaf(v1, wd1.w, fmaf(v2, wd2.w, v3 * wd3.w)));
    #pragma unroll
    for (int off = 1; off <= 8; off <<= 1) {
        ps.x += __shfl_xor(ps.x, off); ps.y += __shfl_xor(ps.y, off);
        ps.z += __shfl_xor(ps.z, off); ps.w += __shfl_xor(ps.w, off);
        pd.x += __shfl_xor(pd.x, off); pd.y += __shfl_xor(pd.y, off);
        pd.z += __shfl_xor(pd.z, off); pd.w += __shfl_xor(pd.w, off);
    }
    if (c == 0) {
        *(float4*)(alsrc2 + (size_t)d * 4) = ps;
        *(float4*)(aldst2 + (size_t)d * 4) = pd;
    }
}

// ---------------- Layer 2 node aggregation over h1o: lane owns dims 4c..4c+3 for ALL 4 heads ----------------
// Shuffle-split weights (lane evaluates one (edge,head) pair per quad) + int4 srccol +
// one-quad-ahead software pipeline. y[d, h*64+k] = z_h[d,k] * 0.25/den_h.

#define EDGE_SH(J, U) { \
    __half2 l_ = bch(U.x), h_ = bch(U.y); \
    __half2 qa = bchi(__shfl(wi, 4 * J + 0, 16)); \
    __half2 qb = bchi(__shfl(wi, 4 * J + 1, 16)); \
    __half2 qc = bchi(__shfl(wi, 4 * J + 2, 16)); \
    __half2 qd = bchi(__shfl(wi, 4 * J + 3, 16)); \
    aA0 = __hfma2(qa, l_, aA0); aA1 = __hfma2(qa, h_, aA1); \
    aB0 = __hfma2(qb, l_, aB0); aB1 = __hfma2(qb, h_, aB1); \
    aC0 = __hfma2(qc, l_, aC0); aC1 = __hfma2(qc, h_, aC1); \
    aD0 = __hfma2(qd, l_, aD0); aD1 = __hfma2(qd, h_, aD1); }

__global__ __launch_bounds__(256) void node2_k(const __half* __restrict__ h1o, const int* __restrict__ srccol,
                                               const float* __restrict__ alsrc, const float* __restrict__ aldst,
                                               const int* __restrict__ rp, const int* __restrict__ cnt,
                                               __half* __restrict__ y, int N) {
    int t = threadIdx.x;
    int d = (blockIdx.x * 256 + t) >> 4;
    if (d >= N) return;
    int c = t & 15;
    int eh = c >> 2;      // edge slot this lane evaluates (0..3)
    int hh = c & 3;       // head this lane evaluates
    const uint2* hb = (const uint2*)h1o;           // 16 uint2 per 64-half row
    float myad = aldst[d * 4 + hh];
    float selfw = WEXP(alsrc[d * 4 + hh] + myad);
    __half2 selfh = __float2half2_rn(selfw);
    int selfi = *(int*)&selfh;
    float mden = (eh == 0) ? selfw : 0.f;
    uint2 u = hb[((size_t)d << 4) + c];
    __half2 lo = bch(u.x), hi = bch(u.y);
    __half2 sA = bchi(__shfl(selfi, 0, 16));
    __half2 sB = bchi(__shfl(selfi, 1, 16));
    __half2 sC = bchi(__shfl(selfi, 2, 16));
    __half2 sD = bchi(__shfl(selfi, 3, 16));
    __half2 aA0 = __hmul2(sA, lo), aA1 = __hmul2(sA, hi);
    __half2 aB0 = __hmul2(sB, lo), aB1 = __hmul2(sB, hi);
    __half2 aC0 = __hmul2(sC, lo), aC1 = __hmul2(sC, hi);
    __half2 aD0 = __hmul2(sD, lo), aD1 = __hmul2(sD, hi);
    int start = rp[d], deg = cnt[d];
    int nq = deg >> 2;
    int i = 0;
    #define N2_PROC(G0, G1, G2, G3, AW) { \
        float w_ = WEXP((AW) + myad); \
        mden += w_; \
        __half2 wh_ = __float2half2_rn(w_); \
        int wi = *(int*)&wh_; \
        EDGE_SH(0, G0) EDGE_SH(1, G1) EDGE_SH(2, G2) EDGE_SH(3, G3) }
    if (nq > 0) {
        i4v sv = ld_i4(srccol + start);
        uint2 g0 = hb[((size_t)(unsigned)sv.x << 4) + c];
        uint2 g1 = hb[((size_t)(unsigned)sv.y << 4) + c];
        uint2 g2 = hb[((size_t)(unsigned)sv.z << 4) + c];
        uint2 g3 = hb[((size_t)(unsigned)sv.w << 4) + c];
        int my = (eh == 0) ? sv.x : (eh == 1) ? sv.y : (eh == 2) ? sv.z : sv.w;
        float aw = alsrc[(size_t)my * 4 + hh];
        i4v nv = (nq > 1) ? ld_i4(srccol + start + 4) : sv;
        for (int q = 1; q < nq; q++) {
            uint2 n0 = hb[((size_t)(unsigned)nv.x << 4) + c];
            uint2 n1 = hb[((size_t)(unsigned)nv.y << 4) + c];
            uint2 n2 = hb[((size_t)(unsigned)nv.z << 4) + c];
            uint2 n3 = hb[((size_t)(unsigned)nv.w << 4) + c];
            int nmy = (eh == 0) ? nv.x : (eh == 1) ? nv.y : (eh == 2) ? nv.z : nv.w;
            float naw = alsrc[(size_t)nmy * 4 + hh];
            i4v nv2 = (q + 1 < nq) ? ld_i4(srccol + start + 4 * (q + 1)) : nv;
            N2_PROC(g0, g1, g2, g3, aw)
            g0 = n0; g1 = n1; g2 = n2; g3 = n3; aw = naw; nv = nv2;
        }
        N2_PROC(g0, g1, g2, g3, aw)
        i = nq << 2;
    }
    for (; i < deg; i++) {
        int s = srccol[start + i];
        uint2 us = hb[((size_t)(unsigned)s << 4) + c];
        float w = WEXP(alsrc[(size_t)s * 4 + hh] + myad);
        mden += (eh == 0) ? w : 0.f;
        __half2 wh = __float2half2_rn(w);
        int wi = *(int*)&wh;
        EDGE_SH(0, us)
    }
    // reduce dens: after xor4+xor8, every lane holds den for head (c&3)
    mden += __shfl_xor(mden, 4, 16);
    mden += __shfl_xor(mden, 8, 16);
    float dnA = __shfl(mden, 0, 16);
    float dnB = __shfl(mden, 1, 16);
    float dnC = __shfl(mden, 2, 16);
    float dnD = __shfl(mden, 3, 16);
    __half2 jA = __float2half2_rn(0.25f / dnA), jB = __float2half2_rn(0.25f / dnB);
    __half2 jC = __float2half2_rn(0.25f / dnC), jD = __float2half2_rn(0.25f / dnD);
    uint2 oA, oB, oC, oD;
    ((__half2*)&oA)[0] = __hmul2(jA, aA0); ((__half2*)&oA)[1] = __hmul2(jA, aA1);
    ((__half2*)&oB)[0] = __hmul2(jB, aB0); ((__half2*)&oB)[1] = __hmul2(jB, aB1);
    ((__half2*)&oC)[0] = __hmul2(jC, aC0); ((__half2*)&oC)[1] = __hmul2(jC, aC1);
    ((__half2*)&oD)[0] = __hmul2(jD, aD0); ((__half2*)&oD)[1] = __hmul2(jD, aD1);
    __half* yp = y + (size_t)d * 256 + 4u * (unsigned)c;
    *(uint2*)(yp)       = oA;
    *(uint2*)(yp + 64)  = oB;
    *(uint2*)(yp + 128) = oC;
    *(uint2*)(yp + 192) = oD;
}

// ---------------- Final: out = logsoftmax(elu(y @ W2s + b2)); chunked fp16 hfma2 inner loop ----------------
// W2s[h*64+k][c] = W2[k][h*32+c]. wk[k2][col] = half2(W2s[2k2][col], W2s[2k2+1][col]).
// 32-row tiles (LDS 33KB -> ~4 blocks/CU). fp16 accumulation over 16-pair chunks, folded to fp32.

__global__ __launch_bounds__(256) void gemm3_k(const __half* __restrict__ y, const float* __restrict__ W2,
                                               const float* __restrict__ bias, float* __restrict__ out, int N) {
    __shared__ unsigned wk[128 * 32];     // 16 KB
    __shared__ unsigned ys[32 * 130];     // 16.6 KB, pad 130
    int t = threadIdx.x;
    for (int i = t; i < 4096; i += 256) {
        int k2 = i >> 5, col = i & 31;
        int hh = k2 >> 5, kk = (2 * k2) & 63;
        float f0 = W2[kk * 128 + hh * 32 + col];
        float f1 = W2[(kk + 1) * 128 + hh * 32 + col];
        __half2 hv = __floats2half2_rn(f0, f1);
        wk[i] = *(unsigned*)&hv;
    }
    int ct = t & 7, rt = t >> 3;          // row rt (0..31); cols 4ct..4ct+3
    float4 b4 = *(const float4*)(bias + 4 * ct);
    int r0 = blockIdx.x << 5;
    for (int i = t; i < 32 * 64; i += 256) {
        int row = i >> 6, k4 = i & 63;
        uint2 v = make_uint2(0u, 0u);
        int r = r0 + row;
        if (r < N) v = *(const uint2*)(y + (size_t)r * 256 + 4 * k4);
        *(uint2*)&ys[row * 130 + 2 * k4] = v;
    }
    __syncthreads();
    float acc[4] = {0.f, 0.f, 0.f, 0.f};
    const unsigned* yr = ys + rt * 130;
    const unsigned* wp = wk + 4 * ct;
    for (int kc = 0; kc < 128; kc += 16) {
        __half2 h0 = __float2half2_rn(0.f), h1 = h0, h2 = h0, h3 = h0;
        #pragma unroll
        for (int j = 0; j < 16; j++) {
            int k2 = kc + j;
            __half2 x2 = bch(yr[k2]);
            uint2 w01 = *(const uint2*)&wp[k2 * 32];
            uint2 w23 = *(const uint2*)&wp[k2 * 32 + 2];
            h0 = __hfma2(x2, bch(w01.x), h0);
            h1 = __hfma2(x2, bch(w01.y), h1);
            h2 = __hfma2(x2, bch(w23.x), h2);
            h3 = __hfma2(x2, bch(w23.y), h3);
        }
        float2 q0 = __half22float2(h0), q1 = __half22float2(h1);
        float2 q2 = __half22float2(h2), q3 = __half22float2(h3);
        acc[0] += q0.x + q0.y;
        acc[1] += q1.x + q1.y;
        acc[2] += q2.x + q2.y;
        acc[3] += q3.x + q3.y;
    }
    int row = r0 + rt;
    float ev0 = acc[0] + b4.x;
    float ev1 = acc[1] + b4.y;
    float ev2 = acc[2] + b4.z;
    float ev3 = acc[3] + b4.w;
    ev0 = ev0 > 0.f ? ev0 : __expf(ev0) - 1.f;
    ev1 = ev1 > 0.f ? ev1 : __expf(ev1) - 1.f;
    ev2 = ev2 > 0.f ? ev2 : __expf(ev2) - 1.f;
    ev3 = ev3 > 0.f ? ev3 : __expf(ev3) - 1.f;
    float mx = fmaxf(fmaxf(ev0, ev1), fmaxf(ev2, ev3));
    #pragma unroll
    for (int off = 1; off <= 4; off <<= 1) mx = fmaxf(mx, __shfl_xor(mx, off));
    float sm = __expf(ev0 - mx) + __expf(ev1 - mx) + __expf(ev2 - mx) + __expf(ev3 - mx);
    #pragma unroll
    for (int off = 1; off <= 4; off <<= 1) sm += __shfl_xor(sm, off);
    float ls = mx + __logf(sm);
    if (row < N) {
        float4 o;
        o.x = ev0 - ls; o.y = ev1 - ls; o.z = ev2 - ls; o.w = ev3 - ls;
        *(float4*)(out + (size_t)row * 32 + 4 * ct) = o;
    }
}

// ---------------- launch ----------------

extern "C" void kernel_launch(void* const* d_in, const int* in_sizes, int n_in,
                              void* d_out, int out_size, void* d_ws, size_t ws_size,
                              hipStream_t stream) {
    const float* x   = (const float*)d_in[0];
    const int*   ei  = (const int*)d_in[1];
    const float* W1  = (const float*)d_in[2];
    const float* as1 = (const float*)d_in[3];
    const float* ad1 = (const float*)d_in[4];
    const float* b1  = (const float*)d_in[5];
    const float* W2  = (const float*)d_in[6];
    const float* as2 = (const float*)d_in[7];
    const float* ad2 = (const float*)d_in[8];
    const float* b2  = (const float*)d_in[9];
    float* out = (float*)d_out;
    int N = in_sizes[0] / 128;
    int E = in_sizes[1] / 2;

    char* base = (char*)d_ws;
    size_t off = 0;
    auto alloc = [&](size_t bytes) -> char* {
        char* p = base + off;
        off = (off + bytes + 255) & ~(size_t)255;
        return p;
    };
    // y [N,256] fp16 (51.2MB) overlays h1h [N,64] fp16 (dead after node1) and
    // pairs [E] uint2 (dead after partB2): both are fully consumed before node2 writes y.
    __half* y     = (__half*)alloc((size_t)N * 256 * 2);
    __half* h1h   = (__half*)y;
    uint2*  pairs = (uint2*)((char*)y + (size_t)N * 64 * 2);
    __half* h1o   = (__half*)alloc((size_t)N * 64 * 2);
    float* alsrc1 = (float*)alloc((size_t)N * 4 * 4);
    float* aldst1 = (float*)alloc((size_t)N * 4 * 4);
    float* alsrc2 = (float*)alloc((size_t)N * 4 * 4);
    float* aldst2 = (float*)alloc((size_t)N * 4 * 4);
    float* was    = (float*)alloc(256 * 4);
    float* wad    = (float*)alloc(256 * 4);
    int* cnt  = (int*)alloc((size_t)N * 4);
    int* rp   = (int*)alloc((size_t)N * 4);
    int* curA = (int*)alloc(256 * 4);
    int* bc   = (int*)alloc(256 * 4);
    int* bb   = (int*)alloc(260 * 4);
    int* srccol = (int*)alloc((size_t)E * 4);

    int nbk = (N + 511) >> 9;       // 512-node buckets
    int ntilesA = (E + TILE - 1) / TILE;
    int nt1 = (N + 63) >> 6;        // 64-row GEMM tiles (gemm1)
    int nt3 = (N + 31) >> 5;        // 32-row tiles (gemm3)

    prew_k<<<1, 256, 0, stream>>>(W2, as2, ad2, was, wad);
    hipMemsetAsync(bc, 0, 256 * 4, stream);
    bhist_k<<<512, 256, 0, stream>>>(ei, bc, E, nbk);
    bscan_k<<<1, 256, 0, stream>>>(bc, bb, curA, nbk);
    partA_k<<<ntilesA, 256, 0, stream>>>(ei, curA, pairs, E, nbk);
    partB2_k<<<nbk, 256, 0, stream>>>(pairs, bb, rp, cnt, srccol, N);

    gemm1_k<<<(nt1 + 1) / 2, 256, 0, stream>>>(x, W1, as1, ad1, h1h, alsrc1, aldst1, N);
    node1_k<<<(N + 15) / 16, 256, 0, stream>>>(h1h, srccol, alsrc1, aldst1, rp, cnt, b1,
                                               was, wad, h1o, alsrc2, aldst2, N);
    node2_k<<<(N + 15) / 16, 256, 0, stream>>>(h1o, srccol, alsrc2, aldst2, rp, cnt, y, N);
    gemm3_k<<<nt3, 256, 0, stream>>>(y, W2, b2, out, N);
}